// Round 1
// baseline (2641.135 us; speedup 1.0000x reference)
//
#include <hip/hip_runtime.h>

#define NB 16
#define NP 2048
#define NR 64
#define NS 64
#define KSEL 40

// ------------------------- static scratch arenas -------------------------
constexpr long aOUT1 = 0;
constexpr long aT1A  = aOUT1 + 16L*2048*128;
constexpr long aT2A  = aT1A  + 16L*2048*6;
constexpr long aZ1   = aT2A  + 16L*2048*6;
constexpr long aM1   = aZ1   + 16L*2048*128;
constexpr long aVALS1= aM1   + 16L*128*128;
constexpr long aDIS1 = aVALS1+ 16L*2048*64;
constexpr long aVALS2= aDIS1 + 16L*2048;
constexpr long aDIS2 = aVALS2+ 16L*2048*64;
constexpr long aXX2  = aDIS2 + 16L*2048;
constexpr long aG4   = aXX2  + 16L*2048;
constexpr long aT1B  = aG4   + 4L*2048*2048;
constexpr long aT2B  = aT1B  + 16L*2048*128;
constexpr long aOUT2 = aT2B  + 16L*2048*128;
constexpr long aZ2   = aOUT2 + 16L*2048*512;
constexpr long aM2   = aZ2   + 16L*2048*512;
constexpr long aVFR  = aM2   + 16L*512*512;
constexpr long aT1R  = aVFR  + 16L*64*128;
constexpr long aT2R  = aT1R  + 16L*64*128;
constexpr long aOUTR = aT2R  + 16L*64*128;
constexpr long aZR   = aOUTR + 16L*64*512;
constexpr long aMR   = aZR   + 16L*64*512;
constexpr long aPOOL = aMR   + 16L*512*512;
constexpr long aFC1O = aPOOL + 16L*1024;
constexpr long aFC2O = aFC1O + 16L*512;
constexpr long FTOT  = aFC2O + 16L*128;

constexpr long iCOLS1 = 0;
constexpr long iCNT1  = iCOLS1 + 16L*2048*64;
constexpr long iCOLS2 = iCNT1  + 16L*2048;
constexpr long iCNT2  = iCOLS2 + 16L*2048*64;
constexpr long ITOT   = iCNT2  + 16L*2048;

__device__ __align__(256) float g_farena[FTOT];
__device__ __align__(256) int   g_iarena[ITOT];

// ------------------------- wave helpers -------------------------
__device__ __forceinline__ float wsum_f(float v){
  #pragma unroll
  for (int s=32;s>0;s>>=1) v += __shfl_xor(v, s, 64);
  return v;
}
__device__ __forceinline__ int wsum_i(int v){
  #pragma unroll
  for (int s=32;s>0;s>>=1) v += __shfl_xor(v, s, 64);
  return v;
}

// exact kth-largest (with multiplicity) via binary search on float bits,
// then masked sum (degree), compaction of (col, A) pairs, dis = 1/sqrt(d).
__device__ __forceinline__ void topk_store(float (&a)[32], int lane, long row,
    int* __restrict__ cols, float* __restrict__ vals,
    int* __restrict__ cnt, float* __restrict__ dis)
{
  unsigned lo = 0u, hi = 0x40000000u;   // [0, 2.0): all A=exp(-dist) live here
  while (hi - lo > 1u){
    unsigned mid = (lo + hi) >> 1;
    float t = __uint_as_float(mid);
    int c = 0;
    #pragma unroll
    for (int q=0;q<32;++q) c += (a[q] >= t) ? 1 : 0;
    c = wsum_i(c);
    if (c >= KSEL) lo = mid; else hi = mid;
  }
  float kth = __uint_as_float(lo);
  float d = 0.f; int kc = 0;
  #pragma unroll
  for (int q=0;q<32;++q){ if (a[q] >= kth){ d += a[q]; kc++; } }
  d = wsum_f(d);
  int tot = wsum_i(kc);
  int incl = kc;
  #pragma unroll
  for (int s=1;s<64;s<<=1){ int u = __shfl_up(incl, s, 64); if (lane >= s) incl += u; }
  int pos = incl - kc;
  int* cp = cols + row*64; float* vp = vals + row*64;
  #pragma unroll
  for (int q=0;q<32;++q){
    if (a[q] >= kth){
      if (pos < 64){ cp[pos] = q*64 + lane; vp[pos] = a[q]; }
      pos++;
    }
  }
  if (lane == 0){
    cnt[row] = tot <= 64 ? tot : 64;
    dis[row] = d > 0.f ? (1.0f / sqrtf(fmaxf(d, 1e-12f))) : 0.f;
  }
}

// ------------------------- KNN kernels -------------------------
// wave per row; 32 affinity values per lane in registers
__global__ __launch_bounds__(256) void knn1_kernel(const float* __restrict__ x,
    int* __restrict__ cols, float* __restrict__ vals, int* __restrict__ cnt,
    float* __restrict__ dis)
{
  int lane = threadIdx.x & 63;
  long row = (long)blockIdx.x*4 + (threadIdx.x >> 6);
  int b = (int)(row >> 11); int i = (int)(row & (NP-1));
  const float* xb = x + (long)b*NP*6;
  float xi[6];
  #pragma unroll
  for (int d2=0; d2<6; ++d2) xi[d2] = xb[(long)i*6 + d2];
  float xxi = 0.f;
  #pragma unroll
  for (int d2=0; d2<6; ++d2) xxi += xi[d2]*xi[d2];
  float a[32];
  #pragma unroll 4
  for (int c=0;c<32;++c){
    int j = c*64 + lane;
    const float* xj = xb + (long)j*6;
    float xxj = 0.f, inr = 0.f;
    #pragma unroll
    for (int d2=0; d2<6; ++d2){ float v = xj[d2]; xxj += v*v; inr += xi[d2]*v; }
    float dist = xxi + xxj - 2.f*inr;
    a[c] = expf(-dist);
  }
  topk_store(a, lane, row, cols, vals, cnt, dis);
}

__global__ __launch_bounds__(256) void knn2_kernel(const float* __restrict__ G,
    const float* __restrict__ xx, int batch0,
    int* __restrict__ cols, float* __restrict__ vals, int* __restrict__ cnt,
    float* __restrict__ dis)
{
  int lane = threadIdx.x & 63;
  long lrow = (long)blockIdx.x*4 + (threadIdx.x >> 6);   // 0..8191
  int lb = (int)(lrow >> 11); int i = (int)(lrow & (NP-1));
  long row = ((long)(batch0+lb) << 11) + i;
  const float* Gr = G + ((long)lb*NP + i)*NP;
  const float* xxb = xx + ((long)(batch0+lb) << 11);
  float xxi = xxb[i];
  float a[32];
  #pragma unroll 4
  for (int c=0;c<32;++c){
    int j = c*64 + lane;
    float dist = xxi + xxb[j] - 2.f*Gr[j];
    a[c] = expf(-dist);
  }
  topk_store(a, lane, row, cols, vals, cnt, dis);
}

// ------------------------- sparse L application -------------------------
// Y = c1*X + c2*T0 - cs * dis_i * sum_j A_ij * dis_j * X_j
__global__ __launch_bounds__(256) void spmm6_kernel(const float* __restrict__ X,
    const float* __restrict__ T0, float* __restrict__ Y,
    const int* __restrict__ cols, const float* __restrict__ vals,
    const int* __restrict__ cnt, const float* __restrict__ dis,
    float c1, float c2, float cs)
{
  long row = (long)blockIdx.x*256 + threadIdx.x;
  int b = (int)(row >> 11);
  const float* Xb = X + ((long)b << 11)*6;
  const float* db = dis + ((long)b << 11);
  float acc[6] = {0,0,0,0,0,0};
  int c = cnt[row];
  const int* cp = cols + row*64; const float* vp = vals + row*64;
  for (int t=0;t<c;++t){
    int j = cp[t];
    float w = vp[t] * db[j];
    const float* xr = Xb + (long)j*6;
    #pragma unroll
    for (int d2=0; d2<6; ++d2) acc[d2] += w * xr[d2];
  }
  float di = dis[row];
  #pragma unroll
  for (int d2=0; d2<6; ++d2)
    Y[row*6+d2] = c1*X[row*6+d2] + c2*T0[row*6+d2] - cs*di*acc[d2];
}

template<int W>
__global__ __launch_bounds__((W >= 256) ? 256 : W) void spmm_kernel(
    const float* __restrict__ X, const float* __restrict__ T0, float* __restrict__ Y,
    const int* __restrict__ cols, const float* __restrict__ vals,
    const int* __restrict__ cnt, const float* __restrict__ dis,
    float c1, float c2, float cs)
{
  constexpr int TPB = (W >= 256) ? 256 : W;
  constexpr int E = W / TPB;
  __shared__ int scol[64];
  __shared__ float sval[64];
  long row = blockIdx.x;
  int b = (int)(row >> 11);
  int tid = threadIdx.x;
  int c = cnt[row];
  if (tid < 64){ scol[tid] = cols[row*64+tid]; sval[tid] = vals[row*64+tid]; }
  __syncthreads();
  const float* Xb = X + ((long)b << 11)*W;
  const float* db = dis + ((long)b << 11);
  float acc[E] = {};
  for (int t=0;t<c;++t){
    int j = scol[t];
    float w = sval[t] * db[j];
    const float* xr = Xb + (long)j*W;
    #pragma unroll
    for (int e=0;e<E;++e) acc[e] += w * xr[tid + e*TPB];
  }
  float di = dis[row];
  #pragma unroll
  for (int e=0;e<E;++e){
    long idx = row*W + tid + e*TPB;
    Y[idx] = c1*X[idx] + c2*T0[idx] - cs*di*acc[e];
  }
}

// ------------------------- conv1 (K=18, direct) -------------------------
__global__ __launch_bounds__(128) void conv1_kernel(const float* __restrict__ x,
    const float* __restrict__ t1, const float* __restrict__ t2,
    const float* __restrict__ w, const float* __restrict__ bias,
    float* __restrict__ out)
{
  long row = blockIdx.x; int o = threadIdx.x;
  float acc = bias[o];
  const float* xr = x + row*6; const float* a1 = t1 + row*6; const float* a2 = t2 + row*6;
  #pragma unroll
  for (int d2=0; d2<6; ++d2){
    acc += xr[d2]*w[d2*128 + o];
    acc += a1[d2]*w[(6+d2)*128 + o];
    acc += a2[d2]*w[(12+d2)*128 + o];
  }
  out[row*128 + o] = fmaxf(acc, 0.f);
}

// ------------------------- generic fp32 tiled GEMM -------------------------
// AM: 0 = A[k*M+m] (KM), 1 = A[m*K+k] (MK), 2 = cheb-concat of 3 [*,128] (MK)
// BMD: 0 = B[k*N+n] (KN), 1 = B[n*K+k] (NK)
template<int AM, int BMD, bool BR>
__global__ __launch_bounds__(256) void gemm_kernel(
    const float* __restrict__ A0, const float* __restrict__ A1, const float* __restrict__ A2,
    const float* __restrict__ Bp, const float* __restrict__ bias,
    float* __restrict__ C, int M, int N, int K, long sA, long sB, long sC)
{
  __shared__ float As[16][68];
  __shared__ float Bs[16][68];
  int bz = blockIdx.z;
  int m0 = blockIdx.x * 64, n0 = blockIdx.y * 64;
  int tid = threadIdx.x;
  int tx = tid & 15, ty = tid >> 4;
  float acc[4][4] = {};
  const float* Ab = A0 + (long)bz*sA;
  const float* Bb = Bp + (long)bz*sB;
  for (int k0 = 0; k0 < K; k0 += 16){
    if (AM == 0){
      int kk = tid >> 4; int mm = (tid & 15) * 4;
      float4 v = *(const float4*)(Ab + (long)(k0+kk)*M + m0 + mm);
      *(float4*)&As[kk][mm] = v;
    } else {
      int rr = tid >> 2, cc = (tid & 3) * 4;
      const float* src;
      if (AM == 2){
        int kg = k0 + cc;
        const float* base = (kg < 128) ? A0 : ((kg < 256) ? A1 : A2);
        src = base + (long)(m0+rr)*128 + (kg & 127);
      } else {
        src = Ab + (long)(m0+rr)*K + k0 + cc;
      }
      float4 v = *(const float4*)src;
      As[cc+0][rr] = v.x; As[cc+1][rr] = v.y; As[cc+2][rr] = v.z; As[cc+3][rr] = v.w;
    }
    if (BMD == 0){
      int kk = tid >> 4; int nn2 = (tid & 15) * 4;
      float4 v = *(const float4*)(Bb + (long)(k0+kk)*N + n0 + nn2);
      *(float4*)&Bs[kk][nn2] = v;
    } else {
      int rr = tid >> 2, cc = (tid & 3) * 4;
      float4 v = *(const float4*)(Bb + (long)(n0+rr)*K + k0 + cc);
      Bs[cc+0][rr] = v.x; Bs[cc+1][rr] = v.y; Bs[cc+2][rr] = v.z; Bs[cc+3][rr] = v.w;
    }
    __syncthreads();
    #pragma unroll
    for (int kk=0; kk<16; ++kk){
      float a4[4], b4[4];
      *(float4*)a4 = *(const float4*)&As[kk][ty*4];
      *(float4*)b4 = *(const float4*)&Bs[kk][tx*4];
      #pragma unroll
      for (int i2=0;i2<4;++i2)
        #pragma unroll
        for (int j2=0;j2<4;++j2)
          acc[i2][j2] += a4[i2]*b4[j2];
    }
    __syncthreads();
  }
  #pragma unroll
  for (int i2=0;i2<4;++i2){
    long m = m0 + ty*4 + i2;
    float r4[4];
    #pragma unroll
    for (int j2=0;j2<4;++j2){
      float v = acc[i2][j2];
      if (BR){ v += bias[n0 + tx*4 + j2]; v = fmaxf(v, 0.f); }
      r4[j2] = v;
    }
    *(float4*)(C + (long)bz*sC + m*N + n0 + tx*4) = *(float4*)r4;
  }
}

// ------------------------- misc kernels -------------------------
__global__ __launch_bounds__(256) void rownorm_kernel(const float* __restrict__ X,
    float* __restrict__ xx)
{
  int lane = threadIdx.x & 63;
  long row = (long)blockIdx.x*4 + (threadIdx.x >> 6);
  const float* p = X + row*128;
  float v0 = p[lane], v1 = p[64+lane];
  float s = wsum_f(v0*v0 + v1*v1);
  if (lane == 0) xx[row] = s;
}

__global__ __launch_bounds__(128) void reeb_pool_kernel(const float* __restrict__ out1,
    const int* __restrict__ sccs, float* __restrict__ VfR)
{
  int br = blockIdx.x; int b = br >> 6;
  int f = threadIdx.x;
  const int* sp = sccs + (long)br*NS;
  const float* ob = out1 + ((long)b << 11)*128;
  float m = -1e30f;
  for (int s=0;s<NS;++s){
    int idx = sp[s];
    m = fmaxf(m, ob[(long)idx*128 + f]);
  }
  VfR[(long)br*128 + f] = m;
}

// Y = cs*(LR @ X) + c2*T0   (dense small Laplacian, [64x64] per batch)
template<int W>
__global__ __launch_bounds__((W>=256)?256:W) void reeb_mm_kernel(const float* __restrict__ L,
    const float* __restrict__ X, const float* __restrict__ T0, float* __restrict__ Y,
    float cs, float c2)
{
  constexpr int TPB = (W>=256)?256:W;
  constexpr int E = W/TPB;
  int br = blockIdx.x; int b = br >> 6; int r = br & 63;
  const float* lr = L + ((long)b*NR + r)*NR;
  const float* Xb = X + (long)b*NR*W;
  int tid = threadIdx.x;
  float acc[E] = {};
  for (int q=0;q<NR;++q){
    float w = lr[q];
    #pragma unroll
    for (int e=0;e<E;++e) acc[e] += w * Xb[(long)q*W + tid + e*TPB];
  }
  #pragma unroll
  for (int e=0;e<E;++e){
    long idx = (long)br*W + tid + e*TPB;
    Y[idx] = cs*acc[e] + c2*T0[idx];
  }
}

__global__ __launch_bounds__(256) void maxpool_kernel(const float* __restrict__ X,
    float* __restrict__ pool, int nrows, int off)
{
  int id = blockIdx.x*256 + threadIdx.x;
  int b = id >> 9, f = id & 511;
  const float* p = X + ((long)b*nrows)*512 + f;
  float m = -1e30f;
  for (int n=0;n<nrows;++n) m = fmaxf(m, p[(long)n*512]);
  pool[(long)b*1024 + off + f] = m;
}

template<bool RELU>
__global__ __launch_bounds__(256) void fc_kernel(const float* __restrict__ in,
    const float* __restrict__ W, const float* __restrict__ bias,
    float* __restrict__ out, int IN, int OUT)
{
  int id = blockIdx.x*256 + threadIdx.x;
  if (id >= 16*OUT) return;
  int b = id / OUT, o = id - b*OUT;
  const float* ip = in + (long)b*IN;
  float acc = bias[o];
  for (int i=0;i<IN;++i) acc += ip[i]*W[(long)i*OUT + o];
  out[(long)b*OUT + o] = RELU ? fmaxf(acc, 0.f) : acc;
}

__global__ __launch_bounds__(256) void sumsq_kernel(const float* __restrict__ X, int n,
    float* __restrict__ tgt)
{
  __shared__ float ps[4];
  int tid = threadIdx.x; int lane = tid & 63, wid = tid >> 6;
  float s = 0.f;
  for (long i = (long)blockIdx.x*256 + tid; i < n; i += (long)gridDim.x*256){
    float v = X[i]; s += v*v;
  }
  s = wsum_f(s);
  if (lane == 0) ps[wid] = s;
  __syncthreads();
  if (tid == 0) atomicAdd(tgt, ps[0]+ps[1]+ps[2]+ps[3]);
}

__global__ __launch_bounds__(256) void wreg_kernel(const float* __restrict__ w1,
    const float* __restrict__ b1, const float* __restrict__ w2, const float* __restrict__ b2,
    const float* __restrict__ w3, const float* __restrict__ b3, float* __restrict__ out9)
{
  __shared__ float ps[3][4];
  int tid = threadIdx.x, lane = tid & 63, wid = tid >> 6;
  float s1 = 0.f, s2 = 0.f, s3 = 0.f;
  for (int i=tid;i<1024;i+=256){ float v = w1[(long)i*512]; s1 += v*v; }
  for (int i=tid;i<512;i+=256){ float v = w2[(long)i*128]; s2 += v*v; }
  if (tid < 128){ float v = w3[(long)tid*40]; s3 = v*v; }
  s1 = wsum_f(s1); s2 = wsum_f(s2); s3 = wsum_f(s3);
  if (lane == 0){ ps[0][wid]=s1; ps[1][wid]=s2; ps[2][wid]=s3; }
  __syncthreads();
  if (tid == 0){
    out9[3] = ps[0][0]+ps[0][1]+ps[0][2]+ps[0][3];
    out9[4] = b1[0]*b1[0];
    out9[5] = ps[1][0]+ps[1][1]+ps[1][2]+ps[1][3];
    out9[6] = b2[0]*b2[0];
    out9[7] = ps[2][0]+ps[2][1]+ps[2][2]+ps[2][3];
    out9[8] = b3[0]*b3[0];
  }
}

// ------------------------- host orchestration -------------------------
extern "C" void kernel_launch(void* const* d_in, const int* in_sizes, int n_in,
                              void* d_out, int out_size, void* d_ws, size_t ws_size,
                              hipStream_t stream)
{
  (void)in_sizes; (void)n_in; (void)d_ws; (void)ws_size; (void)out_size;
  const float* x    = (const float*)d_in[0];
  const float* lapR = (const float*)d_in[1];
  const int*   sccs = (const int*)d_in[2];
  const float* w1   = (const float*)d_in[9];
  const float* b1   = (const float*)d_in[10];
  const float* w2   = (const float*)d_in[11];
  const float* b2   = (const float*)d_in[12];
  const float* wR   = (const float*)d_in[13];
  const float* bRb  = (const float*)d_in[14];
  const float* fw1  = (const float*)d_in[15];
  const float* fb1  = (const float*)d_in[16];
  const float* fw2  = (const float*)d_in[17];
  const float* fb2  = (const float*)d_in[18];
  const float* fw3  = (const float*)d_in[19];
  const float* fb3  = (const float*)d_in[20];
  float* out = (float*)d_out;

  float* Fb = nullptr; int* Ib = nullptr;
  hipGetSymbolAddress((void**)&Fb, HIP_SYMBOL(g_farena));
  hipGetSymbolAddress((void**)&Ib, HIP_SYMBOL(g_iarena));

  float* out1 = Fb + aOUT1;  float* t1a = Fb + aT1A;  float* t2a = Fb + aT2A;
  float* Z1   = Fb + aZ1;    float* M1  = Fb + aM1;
  float* vals1= Fb + aVALS1; float* dis1= Fb + aDIS1;
  float* vals2= Fb + aVALS2; float* dis2= Fb + aDIS2;
  float* xx2  = Fb + aXX2;   float* G4  = Fb + aG4;
  float* t1b  = Fb + aT1B;   float* t2b = Fb + aT2B;
  float* out2 = Fb + aOUT2;  float* Z2  = Fb + aZ2;   float* M2 = Fb + aM2;
  float* VfR  = Fb + aVFR;   float* t1R = Fb + aT1R;  float* t2R= Fb + aT2R;
  float* outR = Fb + aOUTR;  float* ZR  = Fb + aZR;   float* MR = Fb + aMR;
  float* pool = Fb + aPOOL;  float* fc1o= Fb + aFC1O; float* fc2o=Fb + aFC2O;
  int* cols1 = Ib + iCOLS1; int* cnt1 = Ib + iCNT1;
  int* cols2 = Ib + iCOLS2; int* cnt2 = Ib + iCNT2;

  hipMemsetAsync(out + 640, 0, 9*sizeof(float), stream);

  // ---- graph 1 (x, FIN=6) ----
  knn1_kernel<<<dim3(8192),dim3(256),0,stream>>>(x, cols1, vals1, cnt1, dis1);
  spmm6_kernel<<<dim3(128),dim3(256),0,stream>>>(x, x, t1a, cols1, vals1, cnt1, dis1, 1.f, 0.f, 1.f);
  spmm6_kernel<<<dim3(128),dim3(256),0,stream>>>(t1a, x, t2a, cols1, vals1, cnt1, dis1, 2.f, -1.f, 2.f);
  conv1_kernel<<<dim3(32768),dim3(128),0,stream>>>(x, t1a, t2a, w1, b1, out1);
  // reg1 = || out1^T (L1 out1) ||^2
  spmm_kernel<128><<<dim3(32768),dim3(128),0,stream>>>(out1, out1, Z1, cols1, vals1, cnt1, dis1, 1.f, 0.f, 1.f);
  gemm_kernel<0,0,false><<<dim3(2,2,16),dim3(256),0,stream>>>(out1, nullptr, nullptr, Z1, nullptr, M1,
      128,128,2048, (long)NP*128, (long)NP*128, 128L*128);
  sumsq_kernel<<<dim3(512),dim3(256),0,stream>>>(M1, 16*128*128, out+640);
  // Reeb segment-max pooling
  reeb_pool_kernel<<<dim3(1024),dim3(128),0,stream>>>(out1, sccs, VfR);

  // ---- graph 2 (out1, F=128): Gram 4 batches at a time ----
  rownorm_kernel<<<dim3(8192),dim3(256),0,stream>>>(out1, xx2);
  for (int g=0; g<4; ++g){
    const float* Ag = out1 + (long)g*4*NP*128;
    gemm_kernel<1,1,false><<<dim3(32,32,4),dim3(256),0,stream>>>(Ag, nullptr, nullptr, Ag, nullptr, G4,
        2048,2048,128, (long)NP*128, (long)NP*128, (long)NP*NP);
    knn2_kernel<<<dim3(2048),dim3(256),0,stream>>>(G4, xx2, g*4, cols2, vals2, cnt2, dis2);
  }
  spmm_kernel<128><<<dim3(32768),dim3(128),0,stream>>>(out1, out1, t1b, cols2, vals2, cnt2, dis2, 1.f, 0.f, 1.f);
  spmm_kernel<128><<<dim3(32768),dim3(128),0,stream>>>(t1b, out1, t2b, cols2, vals2, cnt2, dis2, 2.f, -1.f, 2.f);
  gemm_kernel<2,0,true><<<dim3(512,8,1),dim3(256),0,stream>>>(out1, t1b, t2b, w2, b2, out2,
      32768,512,384, 0,0,0);
  // reg2
  spmm_kernel<512><<<dim3(32768),dim3(256),0,stream>>>(out2, out2, Z2, cols2, vals2, cnt2, dis2, 1.f, 0.f, 1.f);
  gemm_kernel<0,0,false><<<dim3(8,8,16),dim3(256),0,stream>>>(out2, nullptr, nullptr, Z2, nullptr, M2,
      512,512,2048, (long)NP*512, (long)NP*512, 512L*512);
  sumsq_kernel<<<dim3(512),dim3(256),0,stream>>>(M2, 16*512*512, out+641);

  // ---- Reeb branch ----
  reeb_mm_kernel<128><<<dim3(1024),dim3(128),0,stream>>>(lapR, VfR, VfR, t1R, 1.f, 0.f);
  reeb_mm_kernel<128><<<dim3(1024),dim3(128),0,stream>>>(lapR, t1R, VfR, t2R, 2.f, -1.f);
  gemm_kernel<2,0,true><<<dim3(16,8,1),dim3(256),0,stream>>>(VfR, t1R, t2R, wR, bRb, outR,
      1024,512,384, 0,0,0);
  reeb_mm_kernel<512><<<dim3(1024),dim3(256),0,stream>>>(lapR, outR, outR, ZR, 1.f, 0.f);
  gemm_kernel<0,0,false><<<dim3(8,8,16),dim3(256),0,stream>>>(outR, nullptr, nullptr, ZR, nullptr, MR,
      512,512,64, 64L*512, 64L*512, 512L*512);
  sumsq_kernel<<<dim3(512),dim3(256),0,stream>>>(MR, 16*512*512, out+642);

  // ---- head ----
  maxpool_kernel<<<dim3(32),dim3(256),0,stream>>>(out2, pool, 2048, 512);
  maxpool_kernel<<<dim3(32),dim3(256),0,stream>>>(outR, pool, 64, 0);
  fc_kernel<true ><<<dim3(32),dim3(256),0,stream>>>(pool, fw1, fb1, fc1o, 1024, 512);
  fc_kernel<true ><<<dim3(8),dim3(256),0,stream>>>(fc1o, fw2, fb2, fc2o, 512, 128);
  fc_kernel<false><<<dim3(3),dim3(256),0,stream>>>(fc2o, fw3, fb3, out, 128, 40);
  wreg_kernel<<<dim3(1),dim3(256),0,stream>>>(fw1, fb1, fw2, fb2, fw3, fb3, out+640);
}

// Round 2
// 1402.723 us; speedup vs baseline: 1.8829x; 1.8829x over previous
//
#include <hip/hip_runtime.h>

#define NB 16
#define NP 2048
#define NR 64
#define NS 64
#define KSEL 40

typedef __attribute__((ext_vector_type(8))) short bf16x8;
typedef __attribute__((ext_vector_type(4))) float f32x4;

// ------------------------- static scratch arenas -------------------------
constexpr long aOUT1 = 0;
constexpr long aT1A  = aOUT1 + 16L*2048*128;
constexpr long aT2A  = aT1A  + 16L*2048*6;
constexpr long aZ1   = aT2A  + 16L*2048*6;
constexpr long aM1   = aZ1   + 16L*2048*128;
constexpr long aVALS1= aM1   + 16L*128*128;
constexpr long aDIS1 = aVALS1+ 16L*2048*64;
constexpr long aVALS2= aDIS1 + 16L*2048;
constexpr long aDIS2 = aVALS2+ 16L*2048*64;
constexpr long aXX2  = aDIS2 + 16L*2048;
constexpr long aG4   = aXX2  + 16L*2048;
constexpr long aT1B  = aG4   + 4L*2048*2048;
constexpr long aT2B  = aT1B  + 16L*2048*128;
constexpr long aOUT2 = aT2B  + 16L*2048*128;
constexpr long aZ2   = aOUT2 + 16L*2048*512;
constexpr long aM2   = aZ2   + 16L*2048*512;
constexpr long aVFR  = aM2   + 16L*512*512;
constexpr long aT1R  = aVFR  + 16L*64*128;
constexpr long aT2R  = aT1R  + 16L*64*128;
constexpr long aOUTR = aT2R  + 16L*64*128;
constexpr long aZR   = aOUTR + 16L*64*512;
constexpr long aMR   = aZR   + 16L*64*512;
constexpr long aPOOL = aMR   + 16L*512*512;
constexpr long aFC1O = aPOOL + 16L*1024;
constexpr long aFC2O = aFC1O + 16L*512;
constexpr long aMPP  = aFC2O + 16L*128;
constexpr long FTOT  = aMPP  + 16L*8*512;

constexpr long iCOLS1 = 0;
constexpr long iCNT1  = iCOLS1 + 16L*2048*64;
constexpr long iCOLS2 = iCNT1  + 16L*2048;
constexpr long iCNT2  = iCOLS2 + 16L*2048*64;
constexpr long ITOT   = iCNT2  + 16L*2048;

// bf16 (ushort) arena
constexpr long uOUT1H = 0;
constexpr long uOUT1L = uOUT1H + 16L*2048*128;
constexpr long uT1BH  = uOUT1L + 16L*2048*128;
constexpr long uT1BL  = uT1BH  + 16L*2048*128;
constexpr long uT2BH  = uT1BL  + 16L*2048*128;
constexpr long uT2BL  = uT2BH  + 16L*2048*128;
constexpr long uW2TH  = uT2BL  + 16L*2048*128;
constexpr long uW2TL  = uW2TH  + 512L*384;
constexpr long uVFRH  = uW2TL  + 512L*384;
constexpr long uVFRL  = uVFRH  + 16L*64*128;
constexpr long uT1RH  = uVFRL  + 16L*64*128;
constexpr long uT1RL  = uT1RH  + 16L*64*128;
constexpr long uT2RH  = uT1RL  + 16L*64*128;
constexpr long uT2RL  = uT2RH  + 16L*64*128;
constexpr long uWRTH  = uT2RL  + 16L*64*128;
constexpr long uWRTL  = uWRTH  + 512L*384;
constexpr long uOUT1T = uWRTL  + 512L*384;
constexpr long uZ1T   = uOUT1T + 16L*128*2048;
constexpr long uOUT2T = uZ1T   + 16L*128*2048;
constexpr long uZ2T   = uOUT2T + 16L*512*2048;
constexpr long uOUTRT = uZ2T   + 16L*512*2048;
constexpr long uZRT   = uOUTRT + 16L*512*64;
constexpr long UTOT   = uZRT   + 16L*512*64;

__device__ __align__(256) float  g_farena[FTOT];
__device__ __align__(256) int    g_iarena[ITOT];
__device__ __align__(256) ushort g_uarena[UTOT];

// ------------------------- wave helpers -------------------------
__device__ __forceinline__ float wsum_f(float v){
  #pragma unroll
  for (int s=32;s>0;s>>=1) v += __shfl_xor(v, s, 64);
  return v;
}
__device__ __forceinline__ int wsum_i(int v){
  #pragma unroll
  for (int s=32;s>0;s>>=1) v += __shfl_xor(v, s, 64);
  return v;
}

// ------------------------- top-k machinery -------------------------
__device__ __forceinline__ void topk_store(float (&a)[32], int lane, long row,
    int* __restrict__ cols, float* __restrict__ vals,
    int* __restrict__ cnt, float* __restrict__ dis)
{
  unsigned lo = 0u, hi = 0x40000000u;
  while (hi - lo > 1u){
    unsigned mid = (lo + hi) >> 1;
    float t = __uint_as_float(mid);
    int c = 0;
    #pragma unroll
    for (int q=0;q<32;++q) c += (a[q] >= t) ? 1 : 0;
    c = wsum_i(c);
    if (c >= KSEL) lo = mid; else hi = mid;
  }
  float kth = __uint_as_float(lo);
  float d = 0.f; int kc = 0;
  #pragma unroll
  for (int q=0;q<32;++q){ if (a[q] >= kth){ d += a[q]; kc++; } }
  d = wsum_f(d);
  int tot = wsum_i(kc);
  int incl = kc;
  #pragma unroll
  for (int s=1;s<64;s<<=1){ int u = __shfl_up(incl, s, 64); if (lane >= s) incl += u; }
  int pos = incl - kc;
  int* cp = cols + row*64; float* vp = vals + row*64;
  #pragma unroll
  for (int q=0;q<32;++q){
    if (a[q] >= kth){
      if (pos < 64){ cp[pos] = q*64 + lane; vp[pos] = a[q]; }
      pos++;
    }
  }
  if (lane == 0){
    cnt[row] = tot <= 64 ? tot : 64;
    dis[row] = d > 0.f ? (1.0f / sqrtf(fmaxf(d, 1e-12f))) : 0.f;
  }
}

__global__ __launch_bounds__(256) void knn1_kernel(const float* __restrict__ x,
    int* __restrict__ cols, float* __restrict__ vals, int* __restrict__ cnt,
    float* __restrict__ dis)
{
  int lane = threadIdx.x & 63;
  long row = (long)blockIdx.x*4 + (threadIdx.x >> 6);
  int b = (int)(row >> 11); int i = (int)(row & (NP-1));
  const float* xb = x + (long)b*NP*6;
  float xi[6];
  #pragma unroll
  for (int d2=0; d2<6; ++d2) xi[d2] = xb[(long)i*6 + d2];
  float xxi = 0.f;
  #pragma unroll
  for (int d2=0; d2<6; ++d2) xxi += xi[d2]*xi[d2];
  float a[32];
  #pragma unroll 4
  for (int c=0;c<32;++c){
    int j = c*64 + lane;
    const float* xj = xb + (long)j*6;
    float xxj = 0.f, inr = 0.f;
    #pragma unroll
    for (int d2=0; d2<6; ++d2){ float v = xj[d2]; xxj += v*v; inr += xi[d2]*v; }
    float dist = xxi + xxj - 2.f*inr;
    a[c] = expf(-dist);
  }
  topk_store(a, lane, row, cols, vals, cnt, dis);
}

__global__ __launch_bounds__(256) void knn2_kernel(const float* __restrict__ G,
    const float* __restrict__ xx, int batch0,
    int* __restrict__ cols, float* __restrict__ vals, int* __restrict__ cnt,
    float* __restrict__ dis)
{
  int lane = threadIdx.x & 63;
  long lrow = (long)blockIdx.x*4 + (threadIdx.x >> 6);
  int lb = (int)(lrow >> 11); int i = (int)(lrow & (NP-1));
  long row = ((long)(batch0+lb) << 11) + i;
  const float* Gr = G + ((long)lb*NP + i)*NP;
  const float* xxb = xx + ((long)(batch0+lb) << 11);
  float xxi = xxb[i];
  float a[32];
  #pragma unroll 4
  for (int c=0;c<32;++c){
    int j = c*64 + lane;
    float dist = xxi + xxb[j] - 2.f*Gr[j];
    a[c] = expf(-dist);
  }
  topk_store(a, lane, row, cols, vals, cnt, dis);
}

// ------------------------- sparse L application -------------------------
__global__ __launch_bounds__(256) void spmm6_kernel(const float* __restrict__ X,
    const float* __restrict__ T0, float* __restrict__ Y,
    const int* __restrict__ cols, const float* __restrict__ vals,
    const int* __restrict__ cnt, const float* __restrict__ dis,
    float c1, float c2, float cs)
{
  long row = (long)blockIdx.x*256 + threadIdx.x;
  int b = (int)(row >> 11);
  const float* Xb = X + ((long)b << 11)*6;
  const float* db = dis + ((long)b << 11);
  float acc[6] = {0,0,0,0,0,0};
  int c = cnt[row];
  const int* cp = cols + row*64; const float* vp = vals + row*64;
  for (int t=0;t<c;++t){
    int j = cp[t];
    float w = vp[t] * db[j];
    const float* xr = Xb + (long)j*6;
    #pragma unroll
    for (int d2=0; d2<6; ++d2) acc[d2] += w * xr[d2];
  }
  float di = dis[row];
  #pragma unroll
  for (int d2=0; d2<6; ++d2)
    Y[row*6+d2] = c1*X[row*6+d2] + c2*T0[row*6+d2] - cs*di*acc[d2];
}

template<int W>
__global__ __launch_bounds__((W >= 256) ? 256 : W) void spmm_kernel(
    const float* __restrict__ X, const float* __restrict__ T0, float* __restrict__ Y,
    const int* __restrict__ cols, const float* __restrict__ vals,
    const int* __restrict__ cnt, const float* __restrict__ dis,
    float c1, float c2, float cs)
{
  constexpr int TPB = (W >= 256) ? 256 : W;
  constexpr int E = W / TPB;
  __shared__ int scol[64];
  __shared__ float sval[64];
  long row = blockIdx.x;
  int b = (int)(row >> 11);
  int tid = threadIdx.x;
  int c = cnt[row];
  if (tid < 64){ scol[tid] = cols[row*64+tid]; sval[tid] = vals[row*64+tid]; }
  __syncthreads();
  const float* Xb = X + ((long)b << 11)*W;
  const float* db = dis + ((long)b << 11);
  float acc[E] = {};
  for (int t=0;t<c;++t){
    int j = scol[t];
    float w = sval[t] * db[j];
    const float* xr = Xb + (long)j*W;
    #pragma unroll
    for (int e=0;e<E;++e) acc[e] += w * xr[tid + e*TPB];
  }
  float di = dis[row];
  #pragma unroll
  for (int e=0;e<E;++e){
    long idx = row*W + tid + e*TPB;
    Y[idx] = c1*X[idx] + c2*T0[idx] - cs*di*acc[e];
  }
}

// ------------------------- conv1 (K=18, direct) -------------------------
__global__ __launch_bounds__(128) void conv1_kernel(const float* __restrict__ x,
    const float* __restrict__ t1, const float* __restrict__ t2,
    const float* __restrict__ w, const float* __restrict__ bias,
    float* __restrict__ out)
{
  long row = blockIdx.x; int o = threadIdx.x;
  float acc = bias[o];
  const float* xr = x + row*6; const float* a1 = t1 + row*6; const float* a2 = t2 + row*6;
  #pragma unroll
  for (int d2=0; d2<6; ++d2){
    acc += xr[d2]*w[d2*128 + o];
    acc += a1[d2]*w[(6+d2)*128 + o];
    acc += a2[d2]*w[(12+d2)*128 + o];
  }
  out[row*128 + o] = fmaxf(acc, 0.f);
}

// ------------------------- bf16 packing -------------------------
// hi = truncate-to-bf16(x); lo = truncate-to-bf16(x - hi)
__global__ __launch_bounds__(256) void pack_hilo_kernel(const float* __restrict__ X,
    ushort* __restrict__ H, ushort* __restrict__ L, long n4)
{
  long i = (long)blockIdx.x*256 + threadIdx.x;
  if (i >= n4) return;
  float4 v = *(const float4*)(X + i*4);
  float xs[4] = {v.x, v.y, v.z, v.w};
  ushort h[4], l[4];
  #pragma unroll
  for (int q=0;q<4;++q){
    unsigned u = __float_as_uint(xs[q]);
    h[q] = (ushort)(u >> 16);
    float hf = __uint_as_float(u & 0xffff0000u);
    float r = xs[q] - hf;
    l[q] = (ushort)(__float_as_uint(r) >> 16);
  }
  *(ushort4*)(H + i*4) = make_ushort4(h[0],h[1],h[2],h[3]);
  *(ushort4*)(L + i*4) = make_ushort4(l[0],l[1],l[2],l[3]);
}

// transpose fp32 [R][C] -> bf16 [C][R]; HILO: trunc hi/lo pair, else RNE single
template<bool HILO>
__global__ __launch_bounds__(256) void tpack_kernel(const float* __restrict__ X,
    ushort* __restrict__ H, ushort* __restrict__ L,
    int R, int C, long sIn, long sOut)
{
  __shared__ float tile[32][33];
  int c0 = blockIdx.x*32, r0 = blockIdx.y*32, b = blockIdx.z;
  const float* Xb = X + (long)b*sIn;
  int tx = threadIdx.x & 31, ty = threadIdx.x >> 5;
  #pragma unroll
  for (int rr=ty; rr<32; rr+=8)
    tile[rr][tx] = Xb[(long)(r0+rr)*C + c0+tx];
  __syncthreads();
  #pragma unroll
  for (int cc=ty; cc<32; cc+=8){
    float xv = tile[tx][cc];
    long oidx = (long)b*sOut + (long)(c0+cc)*R + r0 + tx;
    unsigned u = __float_as_uint(xv);
    if (HILO){
      H[oidx] = (ushort)(u >> 16);
      float hf = __uint_as_float(u & 0xffff0000u);
      float r = xv - hf;
      L[oidx] = (ushort)(__float_as_uint(r) >> 16);
    } else {
      u += 0x7fffu + ((u >> 16) & 1u);
      H[oidx] = (ushort)(u >> 16);
    }
  }
}

// ------------------------- bf16 MFMA GEMM -------------------------
// C[m][n] (+= via store) = sum_k A[m][k]*B[n][k]; A:[M][K], B:[N][K] bf16.
// SPLIT: A=Ah+Al, B=Bh+Bl, C ~= Ah*Bh^T + Ah*Bl^T + Al*Bh^T (fp32-accurate).
// CHEB: A is concat of 3 [M][128] slices along K (K=384).
template<bool SPLIT, bool CHEB, bool BR>
__global__ __launch_bounds__(256) void mgemm_kernel(
    const ushort* __restrict__ Ah0, const ushort* __restrict__ Ah1, const ushort* __restrict__ Ah2,
    const ushort* __restrict__ Al0, const ushort* __restrict__ Al1, const ushort* __restrict__ Al2,
    const ushort* __restrict__ Bh, const ushort* __restrict__ Bl,
    const float* __restrict__ bias, float* __restrict__ C,
    int M, int N, int K, long sA, long sB, long sC)
{
  __shared__ ushort AsH[128][40];
  __shared__ ushort BsH[128][40];
  __shared__ ushort AsL[SPLIT?128:1][40];
  __shared__ ushort BsL[SPLIT?128:1][40];
  int bz = blockIdx.z;
  int m0 = blockIdx.x*128, n0 = blockIdx.y*128;
  int tid = threadIdx.x, lane = tid & 63, wid = tid >> 6;
  int wm = (wid & 1)*64, wn = (wid >> 1)*64;
  f32x4 acc[4][4] = {};
  const ushort* Bb  = Bh + (long)bz*sB;
  const ushort* Blb = SPLIT ? (Bl + (long)bz*sB) : (const ushort*)nullptr;
  for (int k0 = 0; k0 < K; k0 += 32){
    #pragma unroll
    for (int it=0; it<2; ++it){
      int e = it*2048 + tid*8;
      int row = e >> 5, col = e & 31;
      const ushort* asrc;
      if (CHEB){
        int kg = k0 + col;
        const ushort* base = (kg < 128) ? Ah0 : ((kg < 256) ? Ah1 : Ah2);
        asrc = base + (long)(m0+row)*128 + (kg & 127);
      } else {
        asrc = Ah0 + (long)bz*sA + (long)(m0+row)*K + k0 + col;
      }
      *(bf16x8*)&AsH[row][col] = *(const bf16x8*)asrc;
      *(bf16x8*)&BsH[row][col] = *(const bf16x8*)(Bb + (long)(n0+row)*K + k0 + col);
      if (SPLIT){
        const ushort* alsrc;
        if (CHEB){
          int kg = k0 + col;
          const ushort* base = (kg < 128) ? Al0 : ((kg < 256) ? Al1 : Al2);
          alsrc = base + (long)(m0+row)*128 + (kg & 127);
        } else {
          alsrc = Al0 + (long)bz*sA + (long)(m0+row)*K + k0 + col;
        }
        *(bf16x8*)&AsL[row][col] = *(const bf16x8*)alsrc;
        *(bf16x8*)&BsL[row][col] = *(const bf16x8*)(Blb + (long)(n0+row)*K + k0 + col);
      }
    }
    __syncthreads();
    int lr = lane & 15, kg = lane >> 4;
    bf16x8 af[4], bfr[4];
    #pragma unroll
    for (int f=0; f<4; ++f){
      af[f]  = *(const bf16x8*)&AsH[wm + f*16 + lr][kg*8];
      bfr[f] = *(const bf16x8*)&BsH[wn + f*16 + lr][kg*8];
    }
    if (SPLIT){
      bf16x8 al[4], bl[4];
      #pragma unroll
      for (int f=0; f<4; ++f){
        al[f] = *(const bf16x8*)&AsL[wm + f*16 + lr][kg*8];
        bl[f] = *(const bf16x8*)&BsL[wn + f*16 + lr][kg*8];
      }
      #pragma unroll
      for (int mf=0; mf<4; ++mf)
        #pragma unroll
        for (int nf=0; nf<4; ++nf){
          acc[mf][nf] = __builtin_amdgcn_mfma_f32_16x16x32_bf16(af[mf], bfr[nf], acc[mf][nf], 0,0,0);
          acc[mf][nf] = __builtin_amdgcn_mfma_f32_16x16x32_bf16(af[mf], bl[nf],  acc[mf][nf], 0,0,0);
          acc[mf][nf] = __builtin_amdgcn_mfma_f32_16x16x32_bf16(al[mf], bfr[nf], acc[mf][nf], 0,0,0);
        }
    } else {
      #pragma unroll
      for (int mf=0; mf<4; ++mf)
        #pragma unroll
        for (int nf=0; nf<4; ++nf)
          acc[mf][nf] = __builtin_amdgcn_mfma_f32_16x16x32_bf16(af[mf], bfr[nf], acc[mf][nf], 0,0,0);
    }
    __syncthreads();
  }
  int lr = lane & 15, l4 = (lane >> 4)*4;
  #pragma unroll
  for (int mf=0; mf<4; ++mf){
    #pragma unroll
    for (int nf=0; nf<4; ++nf){
      int n = n0 + wn + nf*16 + lr;
      float bv = BR ? bias[n] : 0.f;
      #pragma unroll
      for (int r=0; r<4; ++r){
        int m = m0 + wm + mf*16 + l4 + r;
        float v = acc[mf][nf][r];
        if (BR) v = fmaxf(v + bv, 0.f);
        C[(long)bz*sC + (long)m*N + n] = v;
      }
    }
  }
}

// ------------------------- misc kernels -------------------------
__global__ __launch_bounds__(256) void rownorm_kernel(const float* __restrict__ X,
    float* __restrict__ xx)
{
  int lane = threadIdx.x & 63;
  long row = (long)blockIdx.x*4 + (threadIdx.x >> 6);
  const float* p = X + row*128;
  float v0 = p[lane], v1 = p[64+lane];
  float s = wsum_f(v0*v0 + v1*v1);
  if (lane == 0) xx[row] = s;
}

__global__ __launch_bounds__(128) void reeb_pool_kernel(const float* __restrict__ out1,
    const int* __restrict__ sccs, float* __restrict__ VfR)
{
  int br = blockIdx.x; int b = br >> 6;
  int f = threadIdx.x;
  const int* sp = sccs + (long)br*NS;
  const float* ob = out1 + ((long)b << 11)*128;
  float m = -1e30f;
  for (int s=0;s<NS;++s){
    int idx = sp[s];
    m = fmaxf(m, ob[(long)idx*128 + f]);
  }
  VfR[(long)br*128 + f] = m;
}

template<int W>
__global__ __launch_bounds__((W>=256)?256:W) void reeb_mm_kernel(const float* __restrict__ L,
    const float* __restrict__ X, const float* __restrict__ T0, float* __restrict__ Y,
    float cs, float c2)
{
  constexpr int TPB = (W>=256)?256:W;
  constexpr int E = W/TPB;
  int br = blockIdx.x; int b = br >> 6; int r = br & 63;
  const float* lr = L + ((long)b*NR + r)*NR;
  const float* Xb = X + (long)b*NR*W;
  int tid = threadIdx.x;
  float acc[E] = {};
  for (int q=0;q<NR;++q){
    float w = lr[q];
    #pragma unroll
    for (int e=0;e<E;++e) acc[e] += w * Xb[(long)q*W + tid + e*TPB];
  }
  #pragma unroll
  for (int e=0;e<E;++e){
    long idx = (long)br*W + tid + e*TPB;
    Y[idx] = cs*acc[e] + c2*T0[idx];
  }
}

__global__ __launch_bounds__(512) void maxpool1_kernel(const float* __restrict__ X,
    float* __restrict__ part)
{
  int b = blockIdx.x, rc = blockIdx.y; int f = threadIdx.x;
  const float* p = X + ((long)b*2048 + (long)rc*256)*512 + f;
  float m = -1e30f;
  #pragma unroll 4
  for (int r=0;r<256;++r) m = fmaxf(m, p[(long)r*512]);
  part[((long)b*8+rc)*512 + f] = m;
}

__global__ __launch_bounds__(512) void maxpool2_kernel(const float* __restrict__ part,
    const float* __restrict__ outR, float* __restrict__ pool)
{
  int b = blockIdx.x; int f = threadIdx.x;
  const float* pp = part + (long)b*8*512 + f;
  float m = -1e30f;
  #pragma unroll
  for (int r=0;r<8;++r) m = fmaxf(m, pp[r*512]);
  pool[(long)b*1024 + 512 + f] = m;
  const float* rp = outR + (long)b*64*512 + f;
  float mr = -1e30f;
  #pragma unroll 4
  for (int r=0;r<64;++r) mr = fmaxf(mr, rp[(long)r*512]);
  pool[(long)b*1024 + f] = mr;
}

template<bool RELU>
__global__ __launch_bounds__(256) void fc_kernel(const float* __restrict__ in,
    const float* __restrict__ W, const float* __restrict__ bias,
    float* __restrict__ out, int IN, int OUT)
{
  __shared__ float red[4][64];
  int b = blockIdx.x, o0 = blockIdx.y*64;
  int tid = threadIdx.x;
  int ol = tid & 63, q = tid >> 6;
  int o = o0 + ol;
  const float* ip = in + (long)b*IN;
  float acc = 0.f;
  if (o < OUT){
    int kb = IN >> 2;
    int ks = q*kb;
    for (int i=0;i<kb;i+=8){
      #pragma unroll
      for (int u=0;u<8;++u){
        int k = ks + i + u;
        acc += ip[k]*W[(long)k*OUT + o];
      }
    }
  }
  red[q][ol] = acc;
  __syncthreads();
  if (tid < 64){
    int oo = o0 + tid;
    if (oo < OUT){
      float s = red[0][tid]+red[1][tid]+red[2][tid]+red[3][tid] + bias[oo];
      out[(long)b*OUT + oo] = RELU ? fmaxf(s, 0.f) : s;
    }
  }
}

__global__ __launch_bounds__(256) void sumsq_kernel(const float* __restrict__ X, int n,
    float* __restrict__ tgt)
{
  __shared__ float ps[4];
  int tid = threadIdx.x; int lane = tid & 63, wid = tid >> 6;
  float s = 0.f;
  for (long i = (long)blockIdx.x*256 + tid; i < n; i += (long)gridDim.x*256){
    float v = X[i]; s += v*v;
  }
  s = wsum_f(s);
  if (lane == 0) ps[wid] = s;
  __syncthreads();
  if (tid == 0) atomicAdd(tgt, ps[0]+ps[1]+ps[2]+ps[3]);
}

__global__ __launch_bounds__(256) void wreg_kernel(const float* __restrict__ w1,
    const float* __restrict__ b1, const float* __restrict__ w2, const float* __restrict__ b2,
    const float* __restrict__ w3, const float* __restrict__ b3, float* __restrict__ out9)
{
  __shared__ float ps[3][4];
  int tid = threadIdx.x, lane = tid & 63, wid = tid >> 6;
  float s1 = 0.f, s2 = 0.f, s3 = 0.f;
  for (int i=tid;i<1024;i+=256){ float v = w1[(long)i*512]; s1 += v*v; }
  for (int i=tid;i<512;i+=256){ float v = w2[(long)i*128]; s2 += v*v; }
  if (tid < 128){ float v = w3[(long)tid*40]; s3 = v*v; }
  s1 = wsum_f(s1); s2 = wsum_f(s2); s3 = wsum_f(s3);
  if (lane == 0){ ps[0][wid]=s1; ps[1][wid]=s2; ps[2][wid]=s3; }
  __syncthreads();
  if (tid == 0){
    out9[3] = ps[0][0]+ps[0][1]+ps[0][2]+ps[0][3];
    out9[4] = b1[0]*b1[0];
    out9[5] = ps[1][0]+ps[1][1]+ps[1][2]+ps[1][3];
    out9[6] = b2[0]*b2[0];
    out9[7] = ps[2][0]+ps[2][1]+ps[2][2]+ps[2][3];
    out9[8] = b3[0]*b3[0];
  }
}

// ------------------------- host orchestration -------------------------
extern "C" void kernel_launch(void* const* d_in, const int* in_sizes, int n_in,
                              void* d_out, int out_size, void* d_ws, size_t ws_size,
                              hipStream_t stream)
{
  (void)in_sizes; (void)n_in; (void)d_ws; (void)ws_size; (void)out_size;
  const float* x    = (const float*)d_in[0];
  const float* lapR = (const float*)d_in[1];
  const int*   sccs = (const int*)d_in[2];
  const float* w1   = (const float*)d_in[9];
  const float* b1   = (const float*)d_in[10];
  const float* w2   = (const float*)d_in[11];
  const float* b2   = (const float*)d_in[12];
  const float* wR   = (const float*)d_in[13];
  const float* bRb  = (const float*)d_in[14];
  const float* fw1  = (const float*)d_in[15];
  const float* fb1  = (const float*)d_in[16];
  const float* fw2  = (const float*)d_in[17];
  const float* fb2  = (const float*)d_in[18];
  const float* fw3  = (const float*)d_in[19];
  const float* fb3  = (const float*)d_in[20];
  float* out = (float*)d_out;

  float* Fb = nullptr; int* Ib = nullptr; ushort* Ub = nullptr;
  hipGetSymbolAddress((void**)&Fb, HIP_SYMBOL(g_farena));
  hipGetSymbolAddress((void**)&Ib, HIP_SYMBOL(g_iarena));
  hipGetSymbolAddress((void**)&Ub, HIP_SYMBOL(g_uarena));

  float* out1 = Fb + aOUT1;  float* t1a = Fb + aT1A;  float* t2a = Fb + aT2A;
  float* Z1   = Fb + aZ1;    float* M1  = Fb + aM1;
  float* vals1= Fb + aVALS1; float* dis1= Fb + aDIS1;
  float* vals2= Fb + aVALS2; float* dis2= Fb + aDIS2;
  float* xx2  = Fb + aXX2;   float* G4  = Fb + aG4;
  float* t1b  = Fb + aT1B;   float* t2b = Fb + aT2B;
  float* out2 = Fb + aOUT2;  float* Z2  = Fb + aZ2;   float* M2 = Fb + aM2;
  float* VfR  = Fb + aVFR;   float* t1R = Fb + aT1R;  float* t2R= Fb + aT2R;
  float* outR = Fb + aOUTR;  float* ZR  = Fb + aZR;   float* MR = Fb + aMR;
  float* pool = Fb + aPOOL;  float* fc1o= Fb + aFC1O; float* fc2o=Fb + aFC2O;
  float* mpp  = Fb + aMPP;
  int* cols1 = Ib + iCOLS1; int* cnt1 = Ib + iCNT1;
  int* cols2 = Ib + iCOLS2; int* cnt2 = Ib + iCNT2;
  ushort* out1h = Ub + uOUT1H; ushort* out1l = Ub + uOUT1L;
  ushort* t1bh  = Ub + uT1BH;  ushort* t1bl  = Ub + uT1BL;
  ushort* t2bh  = Ub + uT2BH;  ushort* t2bl  = Ub + uT2BL;
  ushort* w2th  = Ub + uW2TH;  ushort* w2tl  = Ub + uW2TL;
  ushort* vfrh  = Ub + uVFRH;  ushort* vfrl  = Ub + uVFRL;
  ushort* t1rh  = Ub + uT1RH;  ushort* t1rl  = Ub + uT1RL;
  ushort* t2rh  = Ub + uT2RH;  ushort* t2rl  = Ub + uT2RL;
  ushort* wrth  = Ub + uWRTH;  ushort* wrtl  = Ub + uWRTL;
  ushort* out1t = Ub + uOUT1T; ushort* z1t   = Ub + uZ1T;
  ushort* out2t = Ub + uOUT2T; ushort* z2t   = Ub + uZ2T;
  ushort* outrt = Ub + uOUTRT; ushort* zrt   = Ub + uZRT;

  hipMemsetAsync(out + 640, 0, 9*sizeof(float), stream);

  // ---- graph 1 (x, FIN=6) ----
  knn1_kernel<<<dim3(8192),dim3(256),0,stream>>>(x, cols1, vals1, cnt1, dis1);
  spmm6_kernel<<<dim3(128),dim3(256),0,stream>>>(x, x, t1a, cols1, vals1, cnt1, dis1, 1.f, 0.f, 1.f);
  spmm6_kernel<<<dim3(128),dim3(256),0,stream>>>(t1a, x, t2a, cols1, vals1, cnt1, dis1, 2.f, -1.f, 2.f);
  conv1_kernel<<<dim3(32768),dim3(128),0,stream>>>(x, t1a, t2a, w1, b1, out1);
  pack_hilo_kernel<<<dim3(4096),dim3(256),0,stream>>>(out1, out1h, out1l, 16L*2048*128/4);

  // reg1 = ||out1^T (L1 out1)||^2  (single-bf16; norm is transpose-immune)
  spmm_kernel<128><<<dim3(32768),dim3(128),0,stream>>>(out1, out1, Z1, cols1, vals1, cnt1, dis1, 1.f, 0.f, 1.f);
  tpack_kernel<false><<<dim3(4,64,16),dim3(256),0,stream>>>(out1, out1t, nullptr, 2048,128, 2048L*128, 128L*2048);
  tpack_kernel<false><<<dim3(4,64,16),dim3(256),0,stream>>>(Z1,   z1t,   nullptr, 2048,128, 2048L*128, 128L*2048);
  mgemm_kernel<false,false,false><<<dim3(1,1,16),dim3(256),0,stream>>>(
      out1t,nullptr,nullptr, nullptr,nullptr,nullptr, z1t,nullptr, nullptr, M1,
      128,128,2048, 128L*2048, 128L*2048, 128L*128);
  sumsq_kernel<<<dim3(512),dim3(256),0,stream>>>(M1, 16*128*128, out+640);
  reeb_pool_kernel<<<dim3(1024),dim3(128),0,stream>>>(out1, sccs, VfR);

  // ---- graph 2 (out1, F=128): split-bf16 Gram, 4 batches at a time ----
  rownorm_kernel<<<dim3(8192),dim3(256),0,stream>>>(out1, xx2);
  for (int g=0; g<4; ++g){
    long off = (long)g*4*NP*128;
    mgemm_kernel<true,false,false><<<dim3(16,16,4),dim3(256),0,stream>>>(
        out1h+off,nullptr,nullptr, out1l+off,nullptr,nullptr, out1h+off, out1l+off, nullptr, G4,
        2048,2048,128, (long)NP*128, (long)NP*128, (long)NP*NP);
    knn2_kernel<<<dim3(2048),dim3(256),0,stream>>>(G4, xx2, g*4, cols2, vals2, cnt2, dis2);
  }
  spmm_kernel<128><<<dim3(32768),dim3(128),0,stream>>>(out1, out1, t1b, cols2, vals2, cnt2, dis2, 1.f, 0.f, 1.f);
  spmm_kernel<128><<<dim3(32768),dim3(128),0,stream>>>(t1b, out1, t2b, cols2, vals2, cnt2, dis2, 2.f, -1.f, 2.f);
  pack_hilo_kernel<<<dim3(4096),dim3(256),0,stream>>>(t1b, t1bh, t1bl, 16L*2048*128/4);
  pack_hilo_kernel<<<dim3(4096),dim3(256),0,stream>>>(t2b, t2bh, t2bl, 16L*2048*128/4);
  tpack_kernel<true><<<dim3(16,12,1),dim3(256),0,stream>>>(w2, w2th, w2tl, 384,512, 0,0);
  mgemm_kernel<true,true,true><<<dim3(256,4,1),dim3(256),0,stream>>>(
      out1h,t1bh,t2bh, out1l,t1bl,t2bl, w2th, w2tl, b2, out2,
      32768,512,384, 0,0,0);
  // reg2
  spmm_kernel<512><<<dim3(32768),dim3(256),0,stream>>>(out2, out2, Z2, cols2, vals2, cnt2, dis2, 1.f, 0.f, 1.f);
  tpack_kernel<false><<<dim3(16,64,16),dim3(256),0,stream>>>(out2, out2t, nullptr, 2048,512, 2048L*512, 512L*2048);
  tpack_kernel<false><<<dim3(16,64,16),dim3(256),0,stream>>>(Z2,   z2t,   nullptr, 2048,512, 2048L*512, 512L*2048);
  mgemm_kernel<false,false,false><<<dim3(4,4,16),dim3(256),0,stream>>>(
      out2t,nullptr,nullptr, nullptr,nullptr,nullptr, z2t,nullptr, nullptr, M2,
      512,512,2048, 512L*2048, 512L*2048, 512L*512);
  sumsq_kernel<<<dim3(512),dim3(256),0,stream>>>(M2, 16*512*512, out+641);

  // ---- Reeb branch ----
  reeb_mm_kernel<128><<<dim3(1024),dim3(128),0,stream>>>(lapR, VfR, VfR, t1R, 1.f, 0.f);
  reeb_mm_kernel<128><<<dim3(1024),dim3(128),0,stream>>>(lapR, t1R, VfR, t2R, 2.f, -1.f);
  pack_hilo_kernel<<<dim3(128),dim3(256),0,stream>>>(VfR, vfrh, vfrl, 16L*64*128/4);
  pack_hilo_kernel<<<dim3(128),dim3(256),0,stream>>>(t1R, t1rh, t1rl, 16L*64*128/4);
  pack_hilo_kernel<<<dim3(128),dim3(256),0,stream>>>(t2R, t2rh, t2rl, 16L*64*128/4);
  tpack_kernel<true><<<dim3(16,12,1),dim3(256),0,stream>>>(wR, wrth, wrtl, 384,512, 0,0);
  mgemm_kernel<true,true,true><<<dim3(8,4,1),dim3(256),0,stream>>>(
      vfrh,t1rh,t2rh, vfrl,t1rl,t2rl, wrth, wrtl, bRb, outR,
      1024,512,384, 0,0,0);
  reeb_mm_kernel<512><<<dim3(1024),dim3(256),0,stream>>>(lapR, outR, outR, ZR, 1.f, 0.f);
  tpack_kernel<false><<<dim3(16,2,16),dim3(256),0,stream>>>(outR, outrt, nullptr, 64,512, 64L*512, 512L*64);
  tpack_kernel<false><<<dim3(16,2,16),dim3(256),0,stream>>>(ZR,   zrt,   nullptr, 64,512, 64L*512, 512L*64);
  mgemm_kernel<false,false,false><<<dim3(4,4,16),dim3(256),0,stream>>>(
      outrt,nullptr,nullptr, nullptr,nullptr,nullptr, zrt,nullptr, nullptr, MR,
      512,512,64, 512L*64, 512L*64, 512L*512);
  sumsq_kernel<<<dim3(512),dim3(256),0,stream>>>(MR, 16*512*512, out+642);

  // ---- head ----
  maxpool1_kernel<<<dim3(16,8),dim3(512),0,stream>>>(out2, mpp);
  maxpool2_kernel<<<dim3(16),dim3(512),0,stream>>>(mpp, outR, pool);
  fc_kernel<true ><<<dim3(16,8),dim3(256),0,stream>>>(pool, fw1, fb1, fc1o, 1024, 512);
  fc_kernel<true ><<<dim3(16,2),dim3(256),0,stream>>>(fc1o, fw2, fb2, fc2o, 512, 128);
  fc_kernel<false><<<dim3(16,1),dim3(256),0,stream>>>(fc2o, fw3, fb3, out, 128, 40);
  wreg_kernel<<<dim3(1),dim3(256),0,stream>>>(fw1, fb1, fw2, fb2, fw3, fb3, out+640);
}

// Round 3
// 1355.644 us; speedup vs baseline: 1.9483x; 1.0347x over previous
//
#include <hip/hip_runtime.h>

#define NB 16
#define NP 2048
#define NR 64
#define NS 64
#define KSEL 40

typedef __attribute__((ext_vector_type(8))) short bf16x8;
typedef __attribute__((ext_vector_type(4))) float f32x4;

// ------------------------- static scratch arenas -------------------------
constexpr long aOUT1 = 0;
constexpr long aT1A  = aOUT1 + 16L*2048*128;
constexpr long aT2A  = aT1A  + 16L*2048*6;
constexpr long aZ1   = aT2A  + 16L*2048*6;
constexpr long aM1   = aZ1   + 16L*2048*128;
constexpr long aVALS1= aM1   + 16L*128*128;
constexpr long aDIS1 = aVALS1+ 16L*2048*64;
constexpr long aVALS2= aDIS1 + 16L*2048;
constexpr long aDIS2 = aVALS2+ 16L*2048*64;
constexpr long aXX2  = aDIS2 + 16L*2048;
constexpr long aXX1  = aXX2  + 16L*2048;
constexpr long aG4   = aXX1  + 16L*2048;
constexpr long aT1B  = aG4   + 4L*2048*2048;
constexpr long aT2B  = aT1B  + 16L*2048*128;
constexpr long aOUT2 = aT2B  + 16L*2048*128;
constexpr long aZ2   = aOUT2 + 16L*2048*512;
constexpr long aM2   = aZ2   + 16L*2048*512;
constexpr long aVFR  = aM2   + 16L*512*512;
constexpr long aT1R  = aVFR  + 16L*64*128;
constexpr long aT2R  = aT1R  + 16L*64*128;
constexpr long aOUTR = aT2R  + 16L*64*128;
constexpr long aZR   = aOUTR + 16L*64*512;
constexpr long aMR   = aZR   + 16L*64*512;
constexpr long aPOOL = aMR   + 16L*512*512;
constexpr long aFC1O = aPOOL + 16L*1024;
constexpr long aFC2O = aFC1O + 16L*512;
constexpr long aMPP  = aFC2O + 16L*128;
constexpr long FTOT  = aMPP  + 16L*8*512;

constexpr long iCOLS1 = 0;
constexpr long iCNT1  = iCOLS1 + 16L*2048*64;
constexpr long iCOLS2 = iCNT1  + 16L*2048;
constexpr long iCNT2  = iCOLS2 + 16L*2048*64;
constexpr long ITOT   = iCNT2  + 16L*2048;

// bf16 (ushort) arena
constexpr long uOUT1H = 0;
constexpr long uOUT1L = uOUT1H + 16L*2048*128;
constexpr long uT1BH  = uOUT1L + 16L*2048*128;
constexpr long uT1BL  = uT1BH  + 16L*2048*128;
constexpr long uT2BH  = uT1BL  + 16L*2048*128;
constexpr long uT2BL  = uT2BH  + 16L*2048*128;
constexpr long uW2TH  = uT2BL  + 16L*2048*128;
constexpr long uW2TL  = uW2TH  + 512L*384;
constexpr long uVFRH  = uW2TL  + 512L*384;
constexpr long uVFRL  = uVFRH  + 16L*64*128;
constexpr long uT1RH  = uVFRL  + 16L*64*128;
constexpr long uT1RL  = uT1RH  + 16L*64*128;
constexpr long uT2RH  = uT1RL  + 16L*64*128;
constexpr long uT2RL  = uT2RH  + 16L*64*128;
constexpr long uWRTH  = uT2RL  + 16L*64*128;
constexpr long uWRTL  = uWRTH  + 512L*384;
constexpr long uOUT1T = uWRTL  + 512L*384;
constexpr long uZ1T   = uOUT1T + 16L*128*2048;
constexpr long uOUT2T = uZ1T   + 16L*128*2048;
constexpr long uZ2T   = uOUT2T + 16L*512*2048;
constexpr long uOUTRT = uZ2T   + 16L*512*2048;
constexpr long uZRT   = uOUTRT + 16L*512*64;
constexpr long UTOT   = uZRT   + 16L*512*64;

__device__ __align__(256) float  g_farena[FTOT];
__device__ __align__(256) int    g_iarena[ITOT];
__device__ __align__(256) ushort g_uarena[UTOT];

// ------------------------- helpers -------------------------
__device__ __forceinline__ float wsum_f(float v){
  #pragma unroll
  for (int s=32;s>0;s>>=1) v += __shfl_xor(v, s, 64);
  return v;
}
__device__ __forceinline__ int wsum_i(int v){
  #pragma unroll
  for (int s=32;s>0;s>>=1) v += __shfl_xor(v, s, 64);
  return v;
}

__device__ __forceinline__ void gl2lds16(const void* g, void* l){
  __builtin_amdgcn_global_load_lds(
      (const __attribute__((address_space(1))) void*)g,
      (__attribute__((address_space(3))) void*)l, 16, 0, 0);
}

// ------------------------- top-k machinery -------------------------
// count(a >= t) across the wave via ballot: compare on VALU, count on SALU.
__device__ __forceinline__ int count_ge(const float (&a)[32], float t){
  int c = 0;
  #pragma unroll
  for (int q=0;q<32;++q)
    c += (int)__popcll(__ballot(a[q] >= t));
  return c;   // wave-uniform
}

__device__ __forceinline__ void topk_store(float (&a)[32], int lane, long row,
    int* __restrict__ cols, float* __restrict__ vals,
    int* __restrict__ cnt, float* __restrict__ dis)
{
  // kth largest (with multiplicity) = largest t with count(>=t) >= KSEL.
  unsigned lo = 0u, hi = 0x3f800001u;   // A = exp(-dist) in (0, 1]
  while (hi - lo > 1u){
    unsigned mid = (lo + hi) >> 1;
    int c = count_ge(a, __uint_as_float(mid));
    if (c >= KSEL) lo = mid; else hi = mid;
  }
  float kth = __uint_as_float(lo);
  float d = 0.f; int kc = 0;
  #pragma unroll
  for (int q=0;q<32;++q){ if (a[q] >= kth){ d += a[q]; kc++; } }
  d = wsum_f(d);
  int tot = wsum_i(kc);
  int incl = kc;
  #pragma unroll
  for (int s=1;s<64;s<<=1){ int u = __shfl_up(incl, s, 64); if (lane >= s) incl += u; }
  int pos = incl - kc;
  int* cp = cols + row*64; float* vp = vals + row*64;
  #pragma unroll
  for (int q=0;q<32;++q){
    if (a[q] >= kth){
      if (pos < 64){ cp[pos] = q*64 + lane; vp[pos] = a[q]; }
      pos++;
    }
  }
  if (lane == 0){
    cnt[row] = tot <= 64 ? tot : 64;
    dis[row] = d > 0.f ? (1.0f / sqrtf(fmaxf(d, 1e-12f))) : 0.f;
  }
}

__global__ __launch_bounds__(256) void xx6_kernel(const float* __restrict__ x,
    float* __restrict__ xx1)
{
  long i = (long)blockIdx.x*256 + threadIdx.x;
  const float* p = x + i*6;
  float2 v0 = *(const float2*)(p);
  float2 v1 = *(const float2*)(p+2);
  float2 v2 = *(const float2*)(p+4);
  xx1[i] = v0.x*v0.x + v0.y*v0.y + v1.x*v1.x + v1.y*v1.y + v2.x*v2.x + v2.y*v2.y;
}

__global__ __launch_bounds__(256) void knn1_kernel(const float* __restrict__ x,
    const float* __restrict__ xx1,
    int* __restrict__ cols, float* __restrict__ vals, int* __restrict__ cnt,
    float* __restrict__ dis)
{
  int lane = threadIdx.x & 63;
  long row = (long)blockIdx.x*4 + (threadIdx.x >> 6);
  int b = (int)(row >> 11); int i = (int)(row & (NP-1));
  const float* xb = x + (long)b*NP*6;
  const float* xxb = xx1 + ((long)b << 11);
  float xi[6];
  #pragma unroll
  for (int d2=0; d2<6; ++d2) xi[d2] = xb[(long)i*6 + d2];
  float xxi = xxb[i];
  float a[32];
  #pragma unroll 4
  for (int c=0;c<32;++c){
    int j = c*64 + lane;
    const float* xj = xb + (long)j*6;
    float2 v0 = *(const float2*)(xj);
    float2 v1 = *(const float2*)(xj+2);
    float2 v2 = *(const float2*)(xj+4);
    float inr = xi[0]*v0.x + xi[1]*v0.y + xi[2]*v1.x + xi[3]*v1.y + xi[4]*v2.x + xi[5]*v2.y;
    a[c] = __expf(2.f*inr - xxi - xxb[j]);
  }
  topk_store(a, lane, row, cols, vals, cnt, dis);
}

__global__ __launch_bounds__(256) void knn2_kernel(const float* __restrict__ G,
    const float* __restrict__ xx, int batch0,
    int* __restrict__ cols, float* __restrict__ vals, int* __restrict__ cnt,
    float* __restrict__ dis)
{
  int lane = threadIdx.x & 63;
  long lrow = (long)blockIdx.x*4 + (threadIdx.x >> 6);
  int lb = (int)(lrow >> 11); int i = (int)(lrow & (NP-1));
  long row = ((long)(batch0+lb) << 11) + i;
  const float* Gr = G + ((long)lb*NP + i)*NP;
  const float* xxb = xx + ((long)(batch0+lb) << 11);
  float xxi = xxb[i];
  float a[32];
  #pragma unroll 4
  for (int c=0;c<32;++c){
    int j = c*64 + lane;
    a[c] = __expf(2.f*Gr[j] - xxi - xxb[j]);
  }
  topk_store(a, lane, row, cols, vals, cnt, dis);
}

// ------------------------- sparse L application -------------------------
__global__ __launch_bounds__(256) void spmm6_kernel(const float* __restrict__ X,
    const float* __restrict__ T0, float* __restrict__ Y,
    const int* __restrict__ cols, const float* __restrict__ vals,
    const int* __restrict__ cnt, const float* __restrict__ dis,
    float c1, float c2, float cs)
{
  long row = (long)blockIdx.x*256 + threadIdx.x;
  int b = (int)(row >> 11);
  const float* Xb = X + ((long)b << 11)*6;
  const float* db = dis + ((long)b << 11);
  float acc[6] = {0,0,0,0,0,0};
  int c = cnt[row];
  const int* cp = cols + row*64; const float* vp = vals + row*64;
  for (int t=0;t<c;++t){
    int j = cp[t];
    float w = vp[t] * db[j];
    const float* xr = Xb + (long)j*6;
    #pragma unroll
    for (int d2=0; d2<6; ++d2) acc[d2] += w * xr[d2];
  }
  float di = dis[row];
  #pragma unroll
  for (int d2=0; d2<6; ++d2)
    Y[row*6+d2] = c1*X[row*6+d2] + c2*T0[row*6+d2] - cs*di*acc[d2];
}

template<int W>
__global__ __launch_bounds__((W >= 256) ? 256 : W) void spmm_kernel(
    const float* __restrict__ X, const float* __restrict__ T0, float* __restrict__ Y,
    const int* __restrict__ cols, const float* __restrict__ vals,
    const int* __restrict__ cnt, const float* __restrict__ dis,
    float c1, float c2, float cs)
{
  constexpr int TPB = (W >= 256) ? 256 : W;
  constexpr int E = W / TPB;
  __shared__ int scol[64];
  __shared__ float sval[64];
  long row = blockIdx.x;
  int b = (int)(row >> 11);
  int tid = threadIdx.x;
  int c = cnt[row];
  if (tid < 64){ scol[tid] = cols[row*64+tid]; sval[tid] = vals[row*64+tid]; }
  __syncthreads();
  const float* Xb = X + ((long)b << 11)*W;
  const float* db = dis + ((long)b << 11);
  float acc[E] = {};
  for (int t=0;t<c;++t){
    int j = scol[t];
    float w = sval[t] * db[j];
    const float* xr = Xb + (long)j*W;
    #pragma unroll
    for (int e=0;e<E;++e) acc[e] += w * xr[tid + e*TPB];
  }
  float di = dis[row];
  #pragma unroll
  for (int e=0;e<E;++e){
    long idx = row*W + tid + e*TPB;
    Y[idx] = c1*X[idx] + c2*T0[idx] - cs*di*acc[e];
  }
}

// ------------------------- conv1 (K=18, direct) -------------------------
__global__ __launch_bounds__(128) void conv1_kernel(const float* __restrict__ x,
    const float* __restrict__ t1, const float* __restrict__ t2,
    const float* __restrict__ w, const float* __restrict__ bias,
    float* __restrict__ out)
{
  long row = blockIdx.x; int o = threadIdx.x;
  float acc = bias[o];
  const float* xr = x + row*6; const float* a1 = t1 + row*6; const float* a2 = t2 + row*6;
  #pragma unroll
  for (int d2=0; d2<6; ++d2){
    acc += xr[d2]*w[d2*128 + o];
    acc += a1[d2]*w[(6+d2)*128 + o];
    acc += a2[d2]*w[(12+d2)*128 + o];
  }
  out[row*128 + o] = fmaxf(acc, 0.f);
}

// ------------------------- bf16 packing -------------------------
__global__ __launch_bounds__(256) void pack_hilo_kernel(const float* __restrict__ X,
    ushort* __restrict__ H, ushort* __restrict__ L, long n4)
{
  long i = (long)blockIdx.x*256 + threadIdx.x;
  if (i >= n4) return;
  float4 v = *(const float4*)(X + i*4);
  float xs[4] = {v.x, v.y, v.z, v.w};
  ushort h[4], l[4];
  #pragma unroll
  for (int q=0;q<4;++q){
    unsigned u = __float_as_uint(xs[q]);
    h[q] = (ushort)(u >> 16);
    float hf = __uint_as_float(u & 0xffff0000u);
    float r = xs[q] - hf;
    l[q] = (ushort)(__float_as_uint(r) >> 16);
  }
  *(ushort4*)(H + i*4) = make_ushort4(h[0],h[1],h[2],h[3]);
  *(ushort4*)(L + i*4) = make_ushort4(l[0],l[1],l[2],l[3]);
}

template<bool HILO>
__global__ __launch_bounds__(256) void tpack_kernel(const float* __restrict__ X,
    ushort* __restrict__ H, ushort* __restrict__ L,
    int R, int C, long sIn, long sOut)
{
  __shared__ float tile[32][33];
  int c0 = blockIdx.x*32, r0 = blockIdx.y*32, b = blockIdx.z;
  const float* Xb = X + (long)b*sIn;
  int tx = threadIdx.x & 31, ty = threadIdx.x >> 5;
  #pragma unroll
  for (int rr=ty; rr<32; rr+=8)
    tile[rr][tx] = Xb[(long)(r0+rr)*C + c0+tx];
  __syncthreads();
  #pragma unroll
  for (int cc=ty; cc<32; cc+=8){
    float xv = tile[tx][cc];
    long oidx = (long)b*sOut + (long)(c0+cc)*R + r0 + tx;
    unsigned u = __float_as_uint(xv);
    if (HILO){
      H[oidx] = (ushort)(u >> 16);
      float hf = __uint_as_float(u & 0xffff0000u);
      float r = xv - hf;
      L[oidx] = (ushort)(__float_as_uint(r) >> 16);
    } else {
      u += 0x7fffu + ((u >> 16) & 1u);
      H[oidx] = (ushort)(u >> 16);
    }
  }
}

// ------------------------- bf16 MFMA GEMM (global_load_lds + swizzle) ----
// C[m][n] = sum_k A[m][k]*B[n][k]; A:[M][K], B:[N][K] bf16 row-major.
// LDS tile: linear [128][32] ushort; 16B granules XOR-swizzled by slot^((row>>1)&3)
// so fragment ds_read_b128 covers all 32 banks (2-way max = free).
template<bool SPLIT, bool CHEB, bool BR>
__global__ __launch_bounds__(256) void mgemm_kernel(
    const ushort* __restrict__ Ah0, const ushort* __restrict__ Ah1, const ushort* __restrict__ Ah2,
    const ushort* __restrict__ Al0, const ushort* __restrict__ Al1, const ushort* __restrict__ Al2,
    const ushort* __restrict__ Bh, const ushort* __restrict__ Bl,
    const float* __restrict__ bias, float* __restrict__ C,
    int M, int N, int K, long sA, long sB, long sC)
{
  __shared__ ushort AsH[128*32];
  __shared__ ushort BsH[128*32];
  __shared__ ushort AsL[SPLIT ? 128*32 : 8];
  __shared__ ushort BsL[SPLIT ? 128*32 : 8];
  int bz = blockIdx.z;
  int m0 = blockIdx.x*128, n0 = blockIdx.y*128;
  int tid = threadIdx.x, lane = tid & 63, wid = tid >> 6;
  int wm = (wid & 1)*64, wn = (wid >> 1)*64;
  f32x4 acc[4][4] = {};
  const ushort* Bb  = Bh + (long)bz*sB;
  const ushort* Blb = SPLIT ? (Bl + (long)bz*sB) : (const ushort*)nullptr;
  const ushort* Ab  = CHEB ? Ah0 : (Ah0 + (long)bz*sA);
  const ushort* Alb = (SPLIT && !CHEB) ? (Al0 + (long)bz*sA) : Al0;

  for (int k0 = 0; k0 < K; k0 += 32){
    // ---- stage: 8 chunks of 1KB per buffer; wave w stages chunks 2w,2w+1
    #pragma unroll
    for (int cc2=0; cc2<2; ++cc2){
      int chunk = wid*2 + cc2;
      int e = chunk*512 + lane*8;          // ushort index in tile
      int row = e >> 5;                    // 0..127
      int slot = (e >> 3) & 3;
      int scol = (slot ^ ((row >> 1) & 3)) * 8;   // swizzled source column
      const ushort* asrc;
      if (CHEB){
        int kg2 = k0 + scol;
        const ushort* base = (kg2 < 128) ? Ah0 : ((kg2 < 256) ? Ah1 : Ah2);
        asrc = base + (long)(m0+row)*128 + (kg2 & 127);
      } else {
        asrc = Ab + (long)(m0+row)*K + k0 + scol;
      }
      gl2lds16(asrc, &AsH[chunk*512]);
      gl2lds16(Bb + (long)(n0+row)*K + k0 + scol, &BsH[chunk*512]);
      if (SPLIT){
        const ushort* alsrc;
        if (CHEB){
          int kg2 = k0 + scol;
          const ushort* base = (kg2 < 128) ? Al0 : ((kg2 < 256) ? Al1 : Al2);
          alsrc = base + (long)(m0+row)*128 + (kg2 & 127);
        } else {
          alsrc = Alb + (long)(m0+row)*K + k0 + scol;
        }
        gl2lds16(alsrc, &AsL[chunk*512]);
        gl2lds16(Blb + (long)(n0+row)*K + k0 + scol, &BsL[chunk*512]);
      }
    }
    __syncthreads();
    int lr = lane & 15, kg = lane >> 4;
    bf16x8 af[4], bfr[4];
    #pragma unroll
    for (int f=0; f<4; ++f){
      int ra = wm + f*16 + lr;
      int rb = wn + f*16 + lr;
      af[f]  = *(const bf16x8*)&AsH[ra*32 + (kg ^ ((ra>>1)&3))*8];
      bfr[f] = *(const bf16x8*)&BsH[rb*32 + (kg ^ ((rb>>1)&3))*8];
    }
    if (SPLIT){
      bf16x8 al[4], bl[4];
      #pragma unroll
      for (int f=0; f<4; ++f){
        int ra = wm + f*16 + lr;
        int rb = wn + f*16 + lr;
        al[f] = *(const bf16x8*)&AsL[ra*32 + (kg ^ ((ra>>1)&3))*8];
        bl[f] = *(const bf16x8*)&BsL[rb*32 + (kg ^ ((rb>>1)&3))*8];
      }
      #pragma unroll
      for (int mf=0; mf<4; ++mf)
        #pragma unroll
        for (int nf=0; nf<4; ++nf){
          acc[mf][nf] = __builtin_amdgcn_mfma_f32_16x16x32_bf16(af[mf], bfr[nf], acc[mf][nf], 0,0,0);
          acc[mf][nf] = __builtin_amdgcn_mfma_f32_16x16x32_bf16(af[mf], bl[nf],  acc[mf][nf], 0,0,0);
          acc[mf][nf] = __builtin_amdgcn_mfma_f32_16x16x32_bf16(al[mf], bfr[nf], acc[mf][nf], 0,0,0);
        }
    } else {
      #pragma unroll
      for (int mf=0; mf<4; ++mf)
        #pragma unroll
        for (int nf=0; nf<4; ++nf)
          acc[mf][nf] = __builtin_amdgcn_mfma_f32_16x16x32_bf16(af[mf], bfr[nf], acc[mf][nf], 0,0,0);
    }
    __syncthreads();
  }
  int lr = lane & 15, l4 = (lane >> 4)*4;
  #pragma unroll
  for (int mf=0; mf<4; ++mf){
    #pragma unroll
    for (int nf=0; nf<4; ++nf){
      int n = n0 + wn + nf*16 + lr;
      float bv = BR ? bias[n] : 0.f;
      #pragma unroll
      for (int r=0; r<4; ++r){
        int m = m0 + wm + mf*16 + l4 + r;
        float v = acc[mf][nf][r];
        if (BR) v = fmaxf(v + bv, 0.f);
        C[(long)bz*sC + (long)m*N + n] = v;
      }
    }
  }
}

// ------------------------- misc kernels -------------------------
__global__ __launch_bounds__(256) void rownorm_kernel(const float* __restrict__ X,
    float* __restrict__ xx)
{
  int lane = threadIdx.x & 63;
  long row = (long)blockIdx.x*4 + (threadIdx.x >> 6);
  const float* p = X + row*128;
  float v0 = p[lane], v1 = p[64+lane];
  float s = wsum_f(v0*v0 + v1*v1);
  if (lane == 0) xx[row] = s;
}

__global__ __launch_bounds__(128) void reeb_pool_kernel(const float* __restrict__ out1,
    const int* __restrict__ sccs, float* __restrict__ VfR)
{
  int br = blockIdx.x; int b = br >> 6;
  int f = threadIdx.x;
  const int* sp = sccs + (long)br*NS;
  const float* ob = out1 + ((long)b << 11)*128;
  float m = -1e30f;
  for (int s=0;s<NS;++s){
    int idx = sp[s];
    m = fmaxf(m, ob[(long)idx*128 + f]);
  }
  VfR[(long)br*128 + f] = m;
}

template<int W>
__global__ __launch_bounds__((W>=256)?256:W) void reeb_mm_kernel(const float* __restrict__ L,
    const float* __restrict__ X, const float* __restrict__ T0, float* __restrict__ Y,
    float cs, float c2)
{
  constexpr int TPB = (W>=256)?256:W;
  constexpr int E = W/TPB;
  int br = blockIdx.x; int b = br >> 6; int r = br & 63;
  const float* lr = L + ((long)b*NR + r)*NR;
  const float* Xb = X + (long)b*NR*W;
  int tid = threadIdx.x;
  float acc[E] = {};
  for (int q=0;q<NR;++q){
    float w = lr[q];
    #pragma unroll
    for (int e=0;e<E;++e) acc[e] += w * Xb[(long)q*W + tid + e*TPB];
  }
  #pragma unroll
  for (int e=0;e<E;++e){
    long idx = (long)br*W + tid + e*TPB;
    Y[idx] = cs*acc[e] + c2*T0[idx];
  }
}

__global__ __launch_bounds__(512) void maxpool1_kernel(const float* __restrict__ X,
    float* __restrict__ part)
{
  int b = blockIdx.x, rc = blockIdx.y; int f = threadIdx.x;
  const float* p = X + ((long)b*2048 + (long)rc*256)*512 + f;
  float m = -1e30f;
  #pragma unroll 4
  for (int r=0;r<256;++r) m = fmaxf(m, p[(long)r*512]);
  part[((long)b*8+rc)*512 + f] = m;
}

__global__ __launch_bounds__(512) void maxpool2_kernel(const float* __restrict__ part,
    const float* __restrict__ outR, float* __restrict__ pool)
{
  int b = blockIdx.x; int f = threadIdx.x;
  const float* pp = part + (long)b*8*512 + f;
  float m = -1e30f;
  #pragma unroll
  for (int r=0;r<8;++r) m = fmaxf(m, pp[r*512]);
  pool[(long)b*1024 + 512 + f] = m;
  const float* rp = outR + (long)b*64*512 + f;
  float mr = -1e30f;
  #pragma unroll 4
  for (int r=0;r<64;++r) mr = fmaxf(mr, rp[(long)r*512]);
  pool[(long)b*1024 + f] = mr;
}

template<bool RELU>
__global__ __launch_bounds__(256) void fc_kernel(const float* __restrict__ in,
    const float* __restrict__ W, const float* __restrict__ bias,
    float* __restrict__ out, int IN, int OUT)
{
  __shared__ float red[4][64];
  int b = blockIdx.x, o0 = blockIdx.y*64;
  int tid = threadIdx.x;
  int ol = tid & 63, q = tid >> 6;
  int o = o0 + ol;
  const float* ip = in + (long)b*IN;
  float acc = 0.f;
  if (o < OUT){
    int kb = IN >> 2;
    int ks = q*kb;
    for (int i=0;i<kb;i+=8){
      #pragma unroll
      for (int u=0;u<8;++u){
        int k = ks + i + u;
        acc += ip[k]*W[(long)k*OUT + o];
      }
    }
  }
  red[q][ol] = acc;
  __syncthreads();
  if (tid < 64){
    int oo = o0 + tid;
    if (oo < OUT){
      float s = red[0][tid]+red[1][tid]+red[2][tid]+red[3][tid] + bias[oo];
      out[(long)b*OUT + oo] = RELU ? fmaxf(s, 0.f) : s;
    }
  }
}

__global__ __launch_bounds__(256) void sumsq_kernel(const float* __restrict__ X, int n,
    float* __restrict__ tgt)
{
  __shared__ float ps[4];
  int tid = threadIdx.x; int lane = tid & 63, wid = tid >> 6;
  float s = 0.f;
  for (long i = (long)blockIdx.x*256 + tid; i < n; i += (long)gridDim.x*256){
    float v = X[i]; s += v*v;
  }
  s = wsum_f(s);
  if (lane == 0) ps[wid] = s;
  __syncthreads();
  if (tid == 0) atomicAdd(tgt, ps[0]+ps[1]+ps[2]+ps[3]);
}

__global__ __launch_bounds__(256) void wreg_kernel(const float* __restrict__ w1,
    const float* __restrict__ b1, const float* __restrict__ w2, const float* __restrict__ b2,
    const float* __restrict__ w3, const float* __restrict__ b3, float* __restrict__ out9)
{
  __shared__ float ps[3][4];
  int tid = threadIdx.x, lane = tid & 63, wid = tid >> 6;
  float s1 = 0.f, s2 = 0.f, s3 = 0.f;
  for (int i=tid;i<1024;i+=256){ float v = w1[(long)i*512]; s1 += v*v; }
  for (int i=tid;i<512;i+=256){ float v = w2[(long)i*128]; s2 += v*v; }
  if (tid < 128){ float v = w3[(long)tid*40]; s3 = v*v; }
  s1 = wsum_f(s1); s2 = wsum_f(s2); s3 = wsum_f(s3);
  if (lane == 0){ ps[0][wid]=s1; ps[1][wid]=s2; ps[2][wid]=s3; }
  __syncthreads();
  if (tid == 0){
    out9[3] = ps[0][0]+ps[0][1]+ps[0][2]+ps[0][3];
    out9[4] = b1[0]*b1[0];
    out9[5] = ps[1][0]+ps[1][1]+ps[1][2]+ps[1][3];
    out9[6] = b2[0]*b2[0];
    out9[7] = ps[2][0]+ps[2][1]+ps[2][2]+ps[2][3];
    out9[8] = b3[0]*b3[0];
  }
}

// ------------------------- host orchestration -------------------------
extern "C" void kernel_launch(void* const* d_in, const int* in_sizes, int n_in,
                              void* d_out, int out_size, void* d_ws, size_t ws_size,
                              hipStream_t stream)
{
  (void)in_sizes; (void)n_in; (void)d_ws; (void)ws_size; (void)out_size;
  const float* x    = (const float*)d_in[0];
  const float* lapR = (const float*)d_in[1];
  const int*   sccs = (const int*)d_in[2];
  const float* w1   = (const float*)d_in[9];
  const float* b1   = (const float*)d_in[10];
  const float* w2   = (const float*)d_in[11];
  const float* b2   = (const float*)d_in[12];
  const float* wR   = (const float*)d_in[13];
  const float* bRb  = (const float*)d_in[14];
  const float* fw1  = (const float*)d_in[15];
  const float* fb1  = (const float*)d_in[16];
  const float* fw2  = (const float*)d_in[17];
  const float* fb2  = (const float*)d_in[18];
  const float* fw3  = (const float*)d_in[19];
  const float* fb3  = (const float*)d_in[20];
  float* out = (float*)d_out;

  float* Fb = nullptr; int* Ib = nullptr; ushort* Ub = nullptr;
  hipGetSymbolAddress((void**)&Fb, HIP_SYMBOL(g_farena));
  hipGetSymbolAddress((void**)&Ib, HIP_SYMBOL(g_iarena));
  hipGetSymbolAddress((void**)&Ub, HIP_SYMBOL(g_uarena));

  float* out1 = Fb + aOUT1;  float* t1a = Fb + aT1A;  float* t2a = Fb + aT2A;
  float* Z1   = Fb + aZ1;    float* M1  = Fb + aM1;
  float* vals1= Fb + aVALS1; float* dis1= Fb + aDIS1;
  float* vals2= Fb + aVALS2; float* dis2= Fb + aDIS2;
  float* xx2  = Fb + aXX2;   float* xx1 = Fb + aXX1;  float* G4  = Fb + aG4;
  float* t1b  = Fb + aT1B;   float* t2b = Fb + aT2B;
  float* out2 = Fb + aOUT2;  float* Z2  = Fb + aZ2;   float* M2 = Fb + aM2;
  float* VfR  = Fb + aVFR;   float* t1R = Fb + aT1R;  float* t2R= Fb + aT2R;
  float* outR = Fb + aOUTR;  float* ZR  = Fb + aZR;   float* MR = Fb + aMR;
  float* pool = Fb + aPOOL;  float* fc1o= Fb + aFC1O; float* fc2o=Fb + aFC2O;
  float* mpp  = Fb + aMPP;
  int* cols1 = Ib + iCOLS1; int* cnt1 = Ib + iCNT1;
  int* cols2 = Ib + iCOLS2; int* cnt2 = Ib + iCNT2;
  ushort* out1h = Ub + uOUT1H; ushort* out1l = Ub + uOUT1L;
  ushort* t1bh  = Ub + uT1BH;  ushort* t1bl  = Ub + uT1BL;
  ushort* t2bh  = Ub + uT2BH;  ushort* t2bl  = Ub + uT2BL;
  ushort* w2th  = Ub + uW2TH;  ushort* w2tl  = Ub + uW2TL;
  ushort* vfrh  = Ub + uVFRH;  ushort* vfrl  = Ub + uVFRL;
  ushort* t1rh  = Ub + uT1RH;  ushort* t1rl  = Ub + uT1RL;
  ushort* t2rh  = Ub + uT2RH;  ushort* t2rl  = Ub + uT2RL;
  ushort* wrth  = Ub + uWRTH;  ushort* wrtl  = Ub + uWRTL;
  ushort* out1t = Ub + uOUT1T; ushort* z1t   = Ub + uZ1T;
  ushort* out2t = Ub + uOUT2T; ushort* z2t   = Ub + uZ2T;
  ushort* outrt = Ub + uOUTRT; ushort* zrt   = Ub + uZRT;

  hipMemsetAsync(out + 640, 0, 9*sizeof(float), stream);

  // ---- graph 1 (x, FIN=6) ----
  xx6_kernel<<<dim3(128),dim3(256),0,stream>>>(x, xx1);
  knn1_kernel<<<dim3(8192),dim3(256),0,stream>>>(x, xx1, cols1, vals1, cnt1, dis1);
  spmm6_kernel<<<dim3(128),dim3(256),0,stream>>>(x, x, t1a, cols1, vals1, cnt1, dis1, 1.f, 0.f, 1.f);
  spmm6_kernel<<<dim3(128),dim3(256),0,stream>>>(t1a, x, t2a, cols1, vals1, cnt1, dis1, 2.f, -1.f, 2.f);
  conv1_kernel<<<dim3(32768),dim3(128),0,stream>>>(x, t1a, t2a, w1, b1, out1);
  pack_hilo_kernel<<<dim3(4096),dim3(256),0,stream>>>(out1, out1h, out1l, 16L*2048*128/4);

  // reg1 = ||out1^T (L1 out1)||^2  (single-bf16; norm transpose-immune)
  spmm_kernel<128><<<dim3(32768),dim3(128),0,stream>>>(out1, out1, Z1, cols1, vals1, cnt1, dis1, 1.f, 0.f, 1.f);
  tpack_kernel<false><<<dim3(4,64,16),dim3(256),0,stream>>>(out1, out1t, nullptr, 2048,128, 2048L*128, 128L*2048);
  tpack_kernel<false><<<dim3(4,64,16),dim3(256),0,stream>>>(Z1,   z1t,   nullptr, 2048,128, 2048L*128, 128L*2048);
  mgemm_kernel<false,false,false><<<dim3(1,1,16),dim3(256),0,stream>>>(
      out1t,nullptr,nullptr, nullptr,nullptr,nullptr, z1t,nullptr, nullptr, M1,
      128,128,2048, 128L*2048, 128L*2048, 128L*128);
  sumsq_kernel<<<dim3(512),dim3(256),0,stream>>>(M1, 16*128*128, out+640);
  reeb_pool_kernel<<<dim3(1024),dim3(128),0,stream>>>(out1, sccs, VfR);

  // ---- graph 2 (out1, F=128): split-bf16 Gram, 4 batches at a time ----
  rownorm_kernel<<<dim3(8192),dim3(256),0,stream>>>(out1, xx2);
  for (int g=0; g<4; ++g){
    long off = (long)g*4*NP*128;
    mgemm_kernel<true,false,false><<<dim3(16,16,4),dim3(256),0,stream>>>(
        out1h+off,nullptr,nullptr, out1l+off,nullptr,nullptr, out1h+off, out1l+off, nullptr, G4,
        2048,2048,128, (long)NP*128, (long)NP*128, (long)NP*NP);
    knn2_kernel<<<dim3(2048),dim3(256),0,stream>>>(G4, xx2, g*4, cols2, vals2, cnt2, dis2);
  }
  spmm_kernel<128><<<dim3(32768),dim3(128),0,stream>>>(out1, out1, t1b, cols2, vals2, cnt2, dis2, 1.f, 0.f, 1.f);
  spmm_kernel<128><<<dim3(32768),dim3(128),0,stream>>>(t1b, out1, t2b, cols2, vals2, cnt2, dis2, 2.f, -1.f, 2.f);
  pack_hilo_kernel<<<dim3(4096),dim3(256),0,stream>>>(t1b, t1bh, t1bl, 16L*2048*128/4);
  pack_hilo_kernel<<<dim3(4096),dim3(256),0,stream>>>(t2b, t2bh, t2bl, 16L*2048*128/4);
  tpack_kernel<true><<<dim3(16,12,1),dim3(256),0,stream>>>(w2, w2th, w2tl, 384,512, 0,0);
  mgemm_kernel<true,true,true><<<dim3(256,4,1),dim3(256),0,stream>>>(
      out1h,t1bh,t2bh, out1l,t1bl,t2bl, w2th, w2tl, b2, out2,
      32768,512,384, 0,0,0);
  // reg2
  spmm_kernel<512><<<dim3(32768),dim3(256),0,stream>>>(out2, out2, Z2, cols2, vals2, cnt2, dis2, 1.f, 0.f, 1.f);
  tpack_kernel<false><<<dim3(16,64,16),dim3(256),0,stream>>>(out2, out2t, nullptr, 2048,512, 2048L*512, 512L*2048);
  tpack_kernel<false><<<dim3(16,64,16),dim3(256),0,stream>>>(Z2,   z2t,   nullptr, 2048,512, 2048L*512, 512L*2048);
  mgemm_kernel<false,false,false><<<dim3(4,4,16),dim3(256),0,stream>>>(
      out2t,nullptr,nullptr, nullptr,nullptr,nullptr, z2t,nullptr, nullptr, M2,
      512,512,2048, 512L*2048, 512L*2048, 512L*512);
  sumsq_kernel<<<dim3(512),dim3(256),0,stream>>>(M2, 16*512*512, out+641);

  // ---- Reeb branch ----
  reeb_mm_kernel<128><<<dim3(1024),dim3(128),0,stream>>>(lapR, VfR, VfR, t1R, 1.f, 0.f);
  reeb_mm_kernel<128><<<dim3(1024),dim3(128),0,stream>>>(lapR, t1R, VfR, t2R, 2.f, -1.f);
  pack_hilo_kernel<<<dim3(128),dim3(256),0,stream>>>(VfR, vfrh, vfrl, 16L*64*128/4);
  pack_hilo_kernel<<<dim3(128),dim3(256),0,stream>>>(t1R, t1rh, t1rl, 16L*64*128/4);
  pack_hilo_kernel<<<dim3(128),dim3(256),0,stream>>>(t2R, t2rh, t2rl, 16L*64*128/4);
  tpack_kernel<true><<<dim3(16,12,1),dim3(256),0,stream>>>(wR, wrth, wrtl, 384,512, 0,0);
  mgemm_kernel<true,true,true><<<dim3(8,4,1),dim3(256),0,stream>>>(
      vfrh,t1rh,t2rh, vfrl,t1rl,t2rl, wrth, wrtl, bRb, outR,
      1024,512,384, 0,0,0);
  reeb_mm_kernel<512><<<dim3(1024),dim3(256),0,stream>>>(lapR, outR, outR, ZR, 1.f, 0.f);
  tpack_kernel<false><<<dim3(16,2,16),dim3(256),0,stream>>>(outR, outrt, nullptr, 64,512, 64L*512, 512L*64);
  tpack_kernel<false><<<dim3(16,2,16),dim3(256),0,stream>>>(ZR,   zrt,   nullptr, 64,512, 64L*512, 512L*64);
  mgemm_kernel<false,false,false><<<dim3(4,4,16),dim3(256),0,stream>>>(
      outrt,nullptr,nullptr, nullptr,nullptr,nullptr, zrt,nullptr, nullptr, MR,
      512,512,64, 512L*64, 512L*64, 512L*512);
  sumsq_kernel<<<dim3(512),dim3(256),0,stream>>>(MR, 16*512*512, out+642);

  // ---- head ----
  maxpool1_kernel<<<dim3(16,8),dim3(512),0,stream>>>(out2, mpp);
  maxpool2_kernel<<<dim3(16),dim3(512),0,stream>>>(mpp, outR, pool);
  fc_kernel<true ><<<dim3(16,8),dim3(256),0,stream>>>(pool, fw1, fb1, fc1o, 1024, 512);
  fc_kernel<true ><<<dim3(16,2),dim3(256),0,stream>>>(fc1o, fw2, fb2, fc2o, 512, 128);
  fc_kernel<false><<<dim3(16,1),dim3(256),0,stream>>>(fc2o, fw3, fb3, out, 128, 40);
  wreg_kernel<<<dim3(1),dim3(256),0,stream>>>(fw1, fb1, fw2, fb2, fw3, fb3, out+640);
}